// Round 9
// baseline (201.979 us; speedup 1.0000x reference)
//
#include <hip/hip_runtime.h>
#include <math.h>

namespace {

constexpr int B_ = 256;
constexpr int R_ = 1152;
constexpr int C_ = 10;
constexpr int O_ = 16;
constexpr int I_ = 8;
constexpr int CO_ = C_ * O_;          // 160
constexpr int WRI_ = C_ * O_ * I_;    // 1280 floats of W per route

constexpr int KS_  = 64;              // r-splits in s-phase
constexpr int RC_  = R_ / KS_;        // 18 routes per s-block

constexpr int NRP_ = 576;             // a-phase route-pairs (RT=2)
constexpr int NBA_ = NRP_ * 2;        // 1152 a-blocks (x2 b-halves)

// fallback tier-3 params
constexpr int KSF_ = 16;
constexpr int RCF_ = R_ / KSF_;       // 72
constexpr int MBF_ = 16;

// ws layout (float offsets) — sA|sB|bij contiguous so k_tr zeroes one range
constexpr size_t XT_OFF    = 0;                          // [R][B][I]
constexpr size_t XT_N      = (size_t)R_ * B_ * I_;       // 2,359,296
constexpr size_t SA_OFF    = XT_OFF + XT_N;              // [CO][B] raw s, iter 0/2
constexpr size_t SAB_N     = (size_t)CO_ * B_;           // 40,960
constexpr size_t SB_OFF    = SA_OFF + SAB_N;             // [CO][B] raw s, iter 1
constexpr size_t BIJ_OFF   = SB_OFF + SAB_N;             // [C][R]
constexpr size_t BIJ_N     = (size_t)C_ * R_;            // 11,520
constexpr size_t ZERO_N    = 2 * SAB_N + BIJ_N;          // 93,440 floats
constexpr size_t FL_TOTAL  = BIJ_OFF + BIJ_N;

__device__ __forceinline__ float rcp_fast(float x) {
#if defined(__has_builtin)
#if __has_builtin(__builtin_amdgcn_rcpf)
    return __builtin_amdgcn_rcpf(x);   // v_rcp_f32, ~1 ulp
#else
    return 1.0f / x;
#endif
#else
    return 1.0f / x;
#endif
}

__device__ __forceinline__ float squashf(float s) {
    // faithful to reference: s^2*s/((1+s^2)*sqrt(s^2)) == s*|s|/(1+s^2)
    return s * fabsf(s) / (1.0f + s * s);
}

// fast variant: v_rcp instead of full div sequence (~5 VALU ops vs ~10).
__device__ __forceinline__ float squash_fast(float s) {
    return s * fabsf(s) * rcp_fast(1.0f + s * s);
}

// ===========================================================================
// k_tr: x[b,r,i] -> xT[r,b,i]; zero sA|sB|bij.  tile 8 b x 32 r.  grid 1152.
// ===========================================================================
__global__ __launch_bounds__(256) void k_tr(const float* __restrict__ x,
                                            float* __restrict__ xT,
                                            float* __restrict__ zbase) {
    __shared__ float t[8][32][8];
    const int tid = threadIdx.x;
    {
        const int gi = blockIdx.x * 256 + tid;
        if (gi < (int)(ZERO_N / 4))
            ((float4*)zbase)[gi] = make_float4(0.f, 0.f, 0.f, 0.f);
    }
    const int r0 = (blockIdx.x % 36) * 32;
    const int b0 = (blockIdx.x / 36) * 8;
    {
        const int rl = tid & 31, bl = tid >> 5;
        const float4* p = (const float4*)(x + ((size_t)(b0 + bl) * R_ + (r0 + rl)) * I_);
        const float4 a0 = p[0], a1 = p[1];
        float* d = &t[bl][rl][0];
        *(float4*)d = a0;
        *(float4*)(d + 4) = a1;
    }
    __syncthreads();
    {
        const int f = tid & 7, rw = tid >> 3;   // f = b-local
        const float* s8 = &t[f][rw][0];
        const float4 a0 = *(const float4*)s8, a1 = *(const float4*)(s8 + 4);
        float* d = xT + ((size_t)(r0 + rw) * B_ + (b0 + f)) * I_;
        *(float4*)d = a0;
        *(float4*)(d + 4) = a1;
    }
}

// ===========================================================================
// k_s8 (KS=64): s_dst[co][b] (+=, atomic) sum_{r in 18-chunk} cw[r,c] *
//               dot(W[r,c,o,:], xT[r,b,:])
// grid 1280: bid = c*128 + ks*2 + bh.  c-stride 128 == 0 (mod 8): all 10
// c-copies of an x-chunk land on one XCD (L2 reuse).
// KS 32->64 vs r8: grid 640->1280 = 5 blocks/CU = 5 waves/SIMD (was 2.5) —
// r8 ledger put s8 at ~13 us vs 4.8 floor with every other counter clean;
// the remaining gap is load-latency under 2.5 waves/SIMD.
// ===========================================================================
template <bool UNIFORM>
__global__ __launch_bounds__(256) void k_s8(const float* __restrict__ xT,
                                            const float* __restrict__ Wm,
                                            const float* __restrict__ bijT,
                                            float* __restrict__ s_dst) {
    __shared__ __align__(16) float wl[RC_ * 128];   // 9.2 KB
    __shared__ float cwch[RC_];
    __shared__ float sred[8];

    const int tid   = threadIdx.x;
    const int lane  = tid & 63;
    const int bid   = blockIdx.x;
    const int c     = bid >> 7;           // 0..9
    const int chunk = bid & 127;
    const int ks    = chunk >> 1;         // 0..63
    const int bh    = chunk & 1;          // 0..1
    const int r0    = ks * RC_;

    // ---- per-block softmax over routes for capsule c -> cwch[0..17] ----
    if (!UNIFORM) {
        const float* bc = bijT + (size_t)c * R_;
        float bv[5];
        float m = -1e30f;
        #pragma unroll
        for (int k = 0; k < 5; ++k) {
            const int r = tid + 256 * k;
            bv[k] = (r < R_) ? bc[r] : -1e30f;
            m = fmaxf(m, bv[k]);
        }
        #pragma unroll
        for (int off = 32; off > 0; off >>= 1)
            m = fmaxf(m, __shfl_down(m, off, 64));
        if (lane == 0) sred[tid >> 6] = m;
        __syncthreads();
        const float bm = fmaxf(fmaxf(sred[0], sred[1]), fmaxf(sred[2], sred[3]));
        float se = 0.f;
        #pragma unroll
        for (int k = 0; k < 5; ++k)
            se += (bv[k] > -1e29f) ? expf(bv[k] - bm) : 0.f;
        #pragma unroll
        for (int off = 32; off > 0; off >>= 1)
            se += __shfl_down(se, off, 64);
        if (lane == 0) sred[4 + (tid >> 6)] = se;
        __syncthreads();
        const float inv = 1.0f / (sred[4] + sred[5] + sred[6] + sred[7]);
        if (tid < RC_) cwch[tid] = expf(bc[r0 + tid] - bm) * inv;
        __syncthreads();
    }

    // ---- stage cw-scaled W chunk: 18 r x 32 f4 = 576 f4 ----
    {
        const float4* src = (const float4*)(Wm + ((size_t)r0 * C_ + c) * 128);
        float4* dst = (float4*)wl;
        #pragma unroll
        for (int k = 0; k < (RC_ * 32 + 255) / 256; ++k) {
            const int idx = tid + 256 * k;
            if (idx < RC_ * 32) {
                const int r = idx >> 5, q = idx & 31;
                float4 wv = src[(size_t)r * (C_ * 32) + q];
                const float cw = UNIFORM ? (1.0f / (float)R_) : cwch[r];
                wv.x *= cw; wv.y *= cw; wv.z *= cw; wv.w *= cw;
                dst[idx] = wv;
            }
        }
    }
    __syncthreads();

    const int o0 = (tid >> 6) * 4;        // wave-uniform -> LDS broadcast reads
    const float* xbase = xT + ((size_t)r0 * B_ + bh * 128 + lane) * I_;

    float acc[4][2];
    #pragma unroll
    for (int oo = 0; oo < 4; ++oo) { acc[oo][0] = 0.f; acc[oo][1] = 0.f; }

    #pragma unroll 2
    for (int r = 0; r < RC_; ++r) {
        const float* xr = xbase + (size_t)r * B_ * I_;
        const float4 a00 = ((const float4*)xr)[0];
        const float4 a01 = ((const float4*)xr)[1];
        const float4 a10 = ((const float4*)(xr + 64 * I_))[0];
        const float4 a11 = ((const float4*)(xr + 64 * I_))[1];
        const float4* wp = (const float4*)&wl[r * 128 + o0 * 8];
        #pragma unroll
        for (int oo = 0; oo < 4; ++oo) {
            const float4 w0 = wp[oo * 2 + 0];
            const float4 w1 = wp[oo * 2 + 1];
            float a = acc[oo][0];
            a = fmaf(a00.x, w0.x, a);
            a = fmaf(a00.y, w0.y, a);
            a = fmaf(a00.z, w0.z, a);
            a = fmaf(a00.w, w0.w, a);
            a = fmaf(a01.x, w1.x, a);
            a = fmaf(a01.y, w1.y, a);
            a = fmaf(a01.z, w1.z, a);
            a = fmaf(a01.w, w1.w, a);
            acc[oo][0] = a;
            float b = acc[oo][1];
            b = fmaf(a10.x, w0.x, b);
            b = fmaf(a10.y, w0.y, b);
            b = fmaf(a10.z, w0.z, b);
            b = fmaf(a10.w, w0.w, b);
            b = fmaf(a11.x, w1.x, b);
            b = fmaf(a11.y, w1.y, b);
            b = fmaf(a11.z, w1.z, b);
            b = fmaf(a11.w, w1.w, b);
            acc[oo][1] = b;
        }
    }

    float* sp = s_dst + (size_t)(c * O_ + o0) * B_ + bh * 128 + lane;
    #pragma unroll
    for (int oo = 0; oo < 4; ++oo) {
        atomicAdd(sp + (size_t)oo * B_, acc[oo][0]);
        atomicAdd(sp + (size_t)oo * B_ + 64, acc[oo][1]);
    }
}

// ===========================================================================
// k_a9: bij[c, r0+rr] += (atomic) (1/B) sum_{o,i} W[r,c,o,i] *
//       (sum_{b in half} squash(s_read[co][b]) * xT[r,b,i])
// r8's a8 split along b: 1152 uniform blocks = 576 route-pairs x 2 b-halves
// of 128 -> ~4 blocks/CU (was 2), no 2r/3r tail.  bid = bh*576 + rp keeps
// both halves of a pair on one XCD (576 % 8 == 0) for x L2 reuse.
// Kept from a8: 4 co/thread (16 fma per LDS read), XOR bank swizzle,
// v_rcp squash.  bij now via atomicAdd (2 contributors), ~20/block.
// 320 thr = 40 co-quads x 8 b-groups of 16.
// ===========================================================================
struct A9Sh {
    float4 xsw[2 * 256];     // swizzled x: 2 routes x 128 b (8 KB)
    float  part[2][320];     // 2.5 KB
};

__global__ __launch_bounds__(320) void k_a9(const float* __restrict__ xT,
                                            const float* __restrict__ Wm,
                                            const float* __restrict__ s_read,
                                            float* __restrict__ s_zero,
                                            float* __restrict__ bijT) {
    __shared__ A9Sh sh;
    const int tid = threadIdx.x;
    const int bid = blockIdx.x;
    const int bh  = (bid >= NRP_) ? 1 : 0;
    const int rp  = bid - bh * NRP_;
    const int r0  = rp * 2;

    if (s_zero != nullptr && bid < 40 && tid < 256) {
        ((float4*)s_zero)[bid * 256 + tid] = make_float4(0.f, 0.f, 0.f, 0.f);
    }

    // ---- stage x half-chunk, swizzled: dst k' = k ^ ((k>>5)&7) ----
    // logical k = rr*256 + b_local*2 + ih; (k>>5)&7 == bg of that element
    // (rr*256>>5 = rr*8 == 0 mod 8).
    {
        const float4* src = (const float4*)(xT + (size_t)r0 * B_ * I_);
        for (int k = tid; k < 2 * 256; k += 320) {
            const int rr = k >> 8, rem = k & 255;
            sh.xsw[k ^ ((k >> 5) & 7)] = src[rr * 512 + bh * 256 + rem];
        }
    }
    __syncthreads();

    const int cq = tid % 40;          // co quad: co = 4cq..4cq+3 (one capsule)
    const int bg = tid / 40;          // 0..7, 16 b each
    const int b0 = bg * 16;           // b-local within the 128-half

    float acc[2][4][8];
    #pragma unroll
    for (int rr = 0; rr < 2; ++rr)
        #pragma unroll
        for (int j = 0; j < 4; ++j)
            #pragma unroll
            for (int i = 0; i < 8; ++i) acc[rr][j][i] = 0.f;

    const float* vbase = s_read + (size_t)(4 * cq) * B_ + bh * 128 + b0;

    #pragma unroll 2
    for (int bb = 0; bb < 16; bb += 4) {
        float va[4][4];               // [co j][b j2], squashed
        #pragma unroll
        for (int j = 0; j < 4; ++j) {
            const float4 t = *(const float4*)(vbase + (size_t)j * B_ + bb);
            va[j][0] = squash_fast(t.x);
            va[j][1] = squash_fast(t.y);
            va[j][2] = squash_fast(t.z);
            va[j][3] = squash_fast(t.w);
        }
        #pragma unroll
        for (int j2 = 0; j2 < 4; ++j2) {
            const int eb = (b0 + bb + j2) * 2;
            #pragma unroll
            for (int rr = 0; rr < 2; ++rr) {
                const float4 x0 = sh.xsw[(rr * 256 + eb) ^ bg];
                const float4 x1 = sh.xsw[(rr * 256 + eb + 1) ^ bg];
                #pragma unroll
                for (int j = 0; j < 4; ++j) {
                    const float w = va[j][j2];
                    acc[rr][j][0] = fmaf(w, x0.x, acc[rr][j][0]);
                    acc[rr][j][1] = fmaf(w, x0.y, acc[rr][j][1]);
                    acc[rr][j][2] = fmaf(w, x0.z, acc[rr][j][2]);
                    acc[rr][j][3] = fmaf(w, x0.w, acc[rr][j][3]);
                    acc[rr][j][4] = fmaf(w, x1.x, acc[rr][j][4]);
                    acc[rr][j][5] = fmaf(w, x1.y, acc[rr][j][5]);
                    acc[rr][j][6] = fmaf(w, x1.z, acc[rr][j][6]);
                    acc[rr][j][7] = fmaf(w, x1.w, acc[rr][j][7]);
                }
            }
        }
    }

    // ---- W-dot epilogue: thread's 4 co are within one capsule ----
    #pragma unroll
    for (int rr = 0; rr < 2; ++rr) {
        const float* wp = Wm + (((size_t)(r0 + rr)) * CO_ + 4 * cq) * I_;
        float psum = 0.f;
        #pragma unroll
        for (int j = 0; j < 4; ++j) {
            const float4 w0 = *(const float4*)(wp + j * 8);
            const float4 w1 = *(const float4*)(wp + j * 8 + 4);
            float p = acc[rr][j][0] * w0.x;
            p = fmaf(acc[rr][j][1], w0.y, p);
            p = fmaf(acc[rr][j][2], w0.z, p);
            p = fmaf(acc[rr][j][3], w0.w, p);
            p = fmaf(acc[rr][j][4], w1.x, p);
            p = fmaf(acc[rr][j][5], w1.y, p);
            p = fmaf(acc[rr][j][6], w1.z, p);
            p = fmaf(acc[rr][j][7], w1.w, p);
            psum += p;
        }
        sh.part[rr][tid] = psum;
    }
    __syncthreads();

    // reduce: per (rr, capsule): 8 bg x 4 cq-of-capsule = 32 partials
    if (tid < 2 * C_) {
        const int r = tid / C_, c2 = tid % C_;
        float s = 0.f;
        #pragma unroll
        for (int g2 = 0; g2 < 8; ++g2)
            #pragma unroll
            for (int q = 0; q < 4; ++q)
                s += sh.part[r][g2 * 40 + c2 * 4 + q];
        atomicAdd(&bijT[(size_t)c2 * R_ + (r0 + r)], s * (1.0f / (float)B_));
    }
}

// ===========================================================================
// k_sqout: out[b,co] = squash(s[co][b]).  grid 160 (=co), 256 thr (=b).
// ===========================================================================
__global__ __launch_bounds__(256) void k_sqout(const float* __restrict__ s,
                                               float* __restrict__ out) {
    const int co = blockIdx.x;
    const int b  = threadIdx.x;
    out[(size_t)b * CO_ + co] = squash_fast(s[(size_t)co * B_ + b]);
}

// ===========================================================================
// FALLBACK tier 3 (tiny ws)
// ===========================================================================
template <bool UNIFORM>
__global__ __launch_bounds__(256) void k_s_f(const float* __restrict__ x,
                                             const float* __restrict__ Wm,
                                             const float* __restrict__ cij,
                                             float* __restrict__ s_out) {
    const int o  = threadIdx.x & 15;
    const int tb = threadIdx.x >> 4;
    const int b  = blockIdx.z * MBF_ + tb;
    const int c  = blockIdx.y;
    const int r0 = blockIdx.x * RCF_;

    const float* xp = x + ((size_t)b * R_ + r0) * I_;
    const float* wp = Wm + (((size_t)r0 * C_ + c) * O_ + o) * I_;
    const float* cp = cij + (size_t)r0 * C_ + c;

    float acc = 0.f;
    #pragma unroll 4
    for (int r = 0; r < RCF_; ++r) {
        const float4 xv0 = *(const float4*)(xp);
        const float4 xv1 = *(const float4*)(xp + 4);
        const float4 wv0 = *(const float4*)(wp);
        const float4 wv1 = *(const float4*)(wp + 4);
        const float p0 = fmaf(xv0.y, wv0.y, xv0.x * wv0.x);
        const float p1 = fmaf(xv0.w, wv0.w, xv0.z * wv0.z);
        const float p2 = fmaf(xv1.y, wv1.y, xv1.x * wv1.x);
        const float p3 = fmaf(xv1.w, wv1.w, xv1.z * wv1.z);
        const float cw = UNIFORM ? (1.0f / (float)R_) : cp[0];
        acc = fmaf(cw, (p0 + p1) + (p2 + p3), acc);
        xp += I_;
        wp += WRI_;
        cp += C_;
    }
    atomicAdd(&s_out[((size_t)b * C_ + c) * O_ + o], acc);
}

__global__ __launch_bounds__(256) void k_a_f(const float* __restrict__ x,
                                             const float* __restrict__ Wm,
                                             const float* __restrict__ s_in,
                                             float* __restrict__ amean) {
    __shared__ __align__(16) float wlds[2 * WRI_];
    __shared__ float red[4][2 * C_];

    const int tid = threadIdx.x;
    const int r0  = blockIdx.x * 2;

    const float* wsrc = Wm + (size_t)r0 * WRI_;
    #pragma unroll
    for (int k = 0; k < 2 * WRI_ / 256; ++k)
        wlds[tid + 256 * k] = wsrc[tid + 256 * k];
    __syncthreads();

    const int b    = tid;
    const int lane = tid & 63;
    const int wv   = tid >> 6;

    float xv[2][I_];
    const float4* xp4 = (const float4*)(x + ((size_t)b * R_ + r0) * I_);
    #pragma unroll
    for (int rr = 0; rr < 2; ++rr) {
        const float4 a0 = xp4[rr * 2 + 0];
        const float4 a1 = xp4[rr * 2 + 1];
        xv[rr][0] = a0.x; xv[rr][1] = a0.y; xv[rr][2] = a0.z; xv[rr][3] = a0.w;
        xv[rr][4] = a1.x; xv[rr][5] = a1.y; xv[rr][6] = a1.z; xv[rr][7] = a1.w;
    }

    #pragma unroll 1
    for (int c = 0; c < C_; ++c) {
        const float4* sp4 = (const float4*)(s_in + ((size_t)b * C_ + c) * O_);
        float v[O_];
        #pragma unroll
        for (int q = 0; q < 4; ++q) {
            const float4 sv = sp4[q];
            v[q * 4 + 0] = squashf(sv.x);
            v[q * 4 + 1] = squashf(sv.y);
            v[q * 4 + 2] = squashf(sv.z);
            v[q * 4 + 3] = squashf(sv.w);
        }
        #pragma unroll 1
        for (int rr = 0; rr < 2; ++rr) {
            const float4* wl4 = (const float4*)&wlds[(rr * C_ + c) * O_ * I_];
            float a = 0.f;
            #pragma unroll
            for (int o = 0; o < O_; ++o) {
                const float4 w0 = wl4[o * 2 + 0];
                const float4 w1 = wl4[o * 2 + 1];
                float u = xv[rr][0] * w0.x;
                u = fmaf(xv[rr][1], w0.y, u);
                u = fmaf(xv[rr][2], w0.z, u);
                u = fmaf(xv[rr][3], w0.w, u);
                u = fmaf(xv[rr][4], w1.x, u);
                u = fmaf(xv[rr][5], w1.y, u);
                u = fmaf(xv[rr][6], w1.z, u);
                u = fmaf(xv[rr][7], w1.w, u);
                a = fmaf(u, v[o], a);
            }
            #pragma unroll
            for (int off = 32; off > 0; off >>= 1)
                a += __shfl_down(a, off, 64);
            if (lane == 0) red[wv][rr * C_ + c] = a;
        }
    }

    __syncthreads();
    if (tid < 2 * C_) {
        const float t = red[0][tid] + red[1][tid] + red[2][tid] + red[3][tid];
        const int rr = tid / C_;
        const int c  = tid % C_;
        amean[(size_t)(r0 + rr) * C_ + c] = t * (1.0f / (float)B_);
    }
}

__global__ __launch_bounds__(256) void k_soft(const float* __restrict__ amean,
                                              float* __restrict__ bij,
                                              float* __restrict__ cij) {
    const int c   = blockIdx.x;
    const int tid = threadIdx.x;
    __shared__ float sred[4];

    float vals[5];
    float m = -1e30f;
    #pragma unroll
    for (int k = 0; k < 5; ++k) {
        const int r = tid + 256 * k;
        if (r < R_) {
            const size_t idx = (size_t)r * C_ + c;
            const float vv = bij[idx] + amean[idx];
            bij[idx] = vv;
            vals[k] = vv;
            m = fmaxf(m, vv);
        } else {
            vals[k] = -1e30f;
        }
    }
    #pragma unroll
    for (int off = 32; off > 0; off >>= 1)
        m = fmaxf(m, __shfl_down(m, off, 64));
    if ((tid & 63) == 0) sred[tid >> 6] = m;
    __syncthreads();
    const float bm = fmaxf(fmaxf(sred[0], sred[1]), fmaxf(sred[2], sred[3]));
    __syncthreads();

    float se = 0.f;
    #pragma unroll
    for (int k = 0; k < 5; ++k)
        se += (vals[k] > -1e29f) ? expf(vals[k] - bm) : 0.f;
    #pragma unroll
    for (int off = 32; off > 0; off >>= 1)
        se += __shfl_down(se, off, 64);
    if ((tid & 63) == 0) sred[tid >> 6] = se;
    __syncthreads();
    const float inv = 1.0f / (sred[0] + sred[1] + sred[2] + sred[3]);

    #pragma unroll
    for (int k = 0; k < 5; ++k) {
        const int r = tid + 256 * k;
        if (r < R_) cij[(size_t)r * C_ + c] = expf(vals[k] - bm) * inv;
    }
}

__global__ __launch_bounds__(256) void k_squash(float* __restrict__ s) {
    const int idx = blockIdx.x * 256 + threadIdx.x;
    if (idx < B_ * CO_) s[idx] = squashf(s[idx]);
}

} // namespace

extern "C" void kernel_launch(void* const* d_in, const int* in_sizes, int n_in,
                              void* d_out, int out_size, void* d_ws, size_t ws_size,
                              hipStream_t stream) {
    const float* x  = (const float*)d_in[0];   // [256,1152,8]
    const float* Wm = (const float*)d_in[1];   // [1152,10,16,8]
    float* out = (float*)d_out;                // [256,10,16] flat = 40960
    float* ws  = (float*)d_ws;

    const size_t need = FL_TOTAL * sizeof(float);

    if (ws_size >= need) {
        // ---------------- main path: 7 nodes ----------------
        float* xT   = ws + XT_OFF;
        float* sA   = ws + SA_OFF;
        float* sB   = ws + SB_OFF;
        float* bijT = ws + BIJ_OFF;

        k_tr<<<1152, 256, 0, stream>>>(x, xT, sA /* = zbase, zeroes sA|sB|bij */);

        // iter 0 (uniform weights; softmax(0) == 1/R)
        k_s8<true><<<C_ * 128, 256, 0, stream>>>(xT, Wm, bijT, sA);
        k_a9<<<NBA_, 320, 0, stream>>>(xT, Wm, sA, nullptr, bijT);

        // iter 1  (sB zeroed by k_tr)
        k_s8<false><<<C_ * 128, 256, 0, stream>>>(xT, Wm, bijT, sB);
        k_a9<<<NBA_, 320, 0, stream>>>(xT, Wm, sB, sA /* zero for iter 2 */, bijT);

        // iter 2
        k_s8<false><<<C_ * 128, 256, 0, stream>>>(xT, Wm, bijT, sA);
        k_sqout<<<CO_, 256, 0, stream>>>(sA, out);
    } else {
        // ---------------- tier 3 ----------------
        float* s_buf = ws;
        float* cij   = ws + 40960;
        float* bij   = cij + R_ * C_;
        float* amean = bij + R_ * C_;

        const dim3 gsf(KSF_, C_, B_ / MBF_);

        hipMemsetAsync(bij, 0, R_ * C_ * sizeof(float), stream);

        hipMemsetAsync(s_buf, 0, B_ * CO_ * sizeof(float), stream);
        k_s_f<true><<<gsf, 256, 0, stream>>>(x, Wm, cij, s_buf);
        k_a_f<<<R_ / 2, 256, 0, stream>>>(x, Wm, s_buf, amean);
        k_soft<<<C_, 256, 0, stream>>>(amean, bij, cij);

        hipMemsetAsync(s_buf, 0, B_ * CO_ * sizeof(float), stream);
        k_s_f<false><<<gsf, 256, 0, stream>>>(x, Wm, cij, s_buf);
        k_a_f<<<R_ / 2, 256, 0, stream>>>(x, Wm, s_buf, amean);
        k_soft<<<C_, 256, 0, stream>>>(amean, bij, cij);

        hipMemsetAsync(out, 0, B_ * CO_ * sizeof(float), stream);
        k_s_f<false><<<gsf, 256, 0, stream>>>(x, Wm, cij, out);
        k_squash<<<(B_ * CO_ + 255) / 256, 256, 0, stream>>>(out);
    }
}

// Round 10
// 195.051 us; speedup vs baseline: 1.0355x; 1.0355x over previous
//
#include <hip/hip_runtime.h>
#include <math.h>

namespace {

constexpr int B_ = 256;
constexpr int R_ = 1152;
constexpr int C_ = 10;
constexpr int O_ = 16;
constexpr int I_ = 8;
constexpr int CO_ = C_ * O_;          // 160
constexpr int WRI_ = C_ * O_ * I_;    // 1280 floats of W per route

constexpr int KS_  = 32;              // r-splits in s-phase
constexpr int RC_  = R_ / KS_;        // 36 routes per s-block

constexpr int NBA_   = 512;           // a-phase blocks (balanced: 2/CU)
constexpr int NBA2_  = 384;           // first 384 blocks: 2 routes each
                                      // last 128 blocks: 3 routes each -> 1152

// fallback tier-3 params
constexpr int KSF_ = 16;
constexpr int RCF_ = R_ / KSF_;       // 72
constexpr int MBF_ = 16;

// ws layout (float offsets) — sA|sB|bij contiguous so k_tr zeroes one range
constexpr size_t XT_OFF    = 0;                          // [R][B][I]
constexpr size_t XT_N      = (size_t)R_ * B_ * I_;       // 2,359,296
constexpr size_t SA_OFF    = XT_OFF + XT_N;              // [CO][B] raw s, iter 0/2
constexpr size_t SAB_N     = (size_t)CO_ * B_;           // 40,960
constexpr size_t SB_OFF    = SA_OFF + SAB_N;             // [CO][B] raw s, iter 1
constexpr size_t BIJ_OFF   = SB_OFF + SAB_N;             // [C][R]
constexpr size_t BIJ_N     = (size_t)C_ * R_;            // 11,520
constexpr size_t ZERO_N    = 2 * SAB_N + BIJ_N;          // 93,440 floats
constexpr size_t FL_TOTAL  = BIJ_OFF + BIJ_N;

__device__ __forceinline__ float rcp_fast(float x) {
#if defined(__has_builtin)
#if __has_builtin(__builtin_amdgcn_rcpf)
    return __builtin_amdgcn_rcpf(x);   // v_rcp_f32, ~1 ulp
#else
    return 1.0f / x;
#endif
#else
    return 1.0f / x;
#endif
}

__device__ __forceinline__ float squashf(float s) {
    // faithful to reference: s^2*s/((1+s^2)*sqrt(s^2)) == s*|s|/(1+s^2)
    return s * fabsf(s) / (1.0f + s * s);
}

// fast variant: v_rcp instead of full div sequence (~5 VALU ops vs ~10).
// r7 counters showed div was ~38% of a-kernel VALU.
__device__ __forceinline__ float squash_fast(float s) {
    return s * fabsf(s) * rcp_fast(1.0f + s * s);
}

// ===========================================================================
// k_tr: x[b,r,i] -> xT[r,b,i]; zero sA|sB|bij.  tile 8 b x 32 r.  grid 1152.
// ===========================================================================
__global__ __launch_bounds__(256) void k_tr(const float* __restrict__ x,
                                            float* __restrict__ xT,
                                            float* __restrict__ zbase) {
    __shared__ float t[8][32][8];
    const int tid = threadIdx.x;
    {
        const int gi = blockIdx.x * 256 + tid;
        if (gi < (int)(ZERO_N / 4))
            ((float4*)zbase)[gi] = make_float4(0.f, 0.f, 0.f, 0.f);
    }
    const int r0 = (blockIdx.x % 36) * 32;
    const int b0 = (blockIdx.x / 36) * 8;
    {
        const int rl = tid & 31, bl = tid >> 5;
        const float4* p = (const float4*)(x + ((size_t)(b0 + bl) * R_ + (r0 + rl)) * I_);
        const float4 a0 = p[0], a1 = p[1];
        float* d = &t[bl][rl][0];
        *(float4*)d = a0;
        *(float4*)(d + 4) = a1;
    }
    __syncthreads();
    {
        const int f = tid & 7, rw = tid >> 3;   // f = b-local
        const float* s8 = &t[f][rw][0];
        const float4 a0 = *(const float4*)s8, a1 = *(const float4*)(s8 + 4);
        float* d = xT + ((size_t)(r0 + rw) * B_ + (b0 + f)) * I_;
        *(float4*)d = a0;
        *(float4*)(d + 4) = a1;
    }
}

// ===========================================================================
// k_s8: s_dst[co][b] (+=, atomic) sum_{r in chunk} cw[r,c]*dot(W[r,c,o,:],xT[r,b,:])
// grid 640: bid = c*64 + ks*2 + bh.  c-stride 64 == 0 (mod 8): all 10
// c-copies of an x-chunk land on one XCD (L2 reuse).  NB=2 (acc[4][2]).
// r9 A/B: KS=64 (grid 1280) was -6 us vs this KS=32 config — atomics double
// and W-chunk reuse halves; kept at KS=32 (best measured, r8 = 196 us).
// ===========================================================================
template <bool UNIFORM>
__global__ __launch_bounds__(256) void k_s8(const float* __restrict__ xT,
                                            const float* __restrict__ Wm,
                                            const float* __restrict__ bijT,
                                            float* __restrict__ s_dst) {
    __shared__ __align__(16) float wl[RC_ * 128];   // 18.4 KB
    __shared__ float cwch[RC_];
    __shared__ float sred[8];

    const int tid   = threadIdx.x;
    const int lane  = tid & 63;
    const int bid   = blockIdx.x;
    const int c     = bid >> 6;           // 0..9
    const int chunk = bid & 63;
    const int ks    = chunk >> 1;         // 0..31
    const int bh    = chunk & 1;          // 0..1
    const int r0    = ks * RC_;

    // ---- per-block softmax over routes for capsule c -> cwch[0..35] ----
    if (!UNIFORM) {
        const float* bc = bijT + (size_t)c * R_;
        float bv[5];
        float m = -1e30f;
        #pragma unroll
        for (int k = 0; k < 5; ++k) {
            const int r = tid + 256 * k;
            bv[k] = (r < R_) ? bc[r] : -1e30f;
            m = fmaxf(m, bv[k]);
        }
        #pragma unroll
        for (int off = 32; off > 0; off >>= 1)
            m = fmaxf(m, __shfl_down(m, off, 64));
        if (lane == 0) sred[tid >> 6] = m;
        __syncthreads();
        const float bm = fmaxf(fmaxf(sred[0], sred[1]), fmaxf(sred[2], sred[3]));
        float se = 0.f;
        #pragma unroll
        for (int k = 0; k < 5; ++k)
            se += (bv[k] > -1e29f) ? expf(bv[k] - bm) : 0.f;
        #pragma unroll
        for (int off = 32; off > 0; off >>= 1)
            se += __shfl_down(se, off, 64);
        if (lane == 0) sred[4 + (tid >> 6)] = se;
        __syncthreads();
        const float inv = 1.0f / (sred[4] + sred[5] + sred[6] + sred[7]);
        if (tid < RC_) cwch[tid] = expf(bc[r0 + tid] - bm) * inv;
        __syncthreads();
    }

    // ---- stage cw-scaled W chunk: 36 r x 32 f4 = 1152 f4 ----
    {
        const float4* src = (const float4*)(Wm + ((size_t)r0 * C_ + c) * 128);
        float4* dst = (float4*)wl;
        #pragma unroll
        for (int k = 0; k < (RC_ * 32 + 255) / 256; ++k) {
            const int idx = tid + 256 * k;
            if (idx < RC_ * 32) {
                const int r = idx >> 5, q = idx & 31;
                float4 wv = src[(size_t)r * (C_ * 32) + q];
                const float cw = UNIFORM ? (1.0f / (float)R_) : cwch[r];
                wv.x *= cw; wv.y *= cw; wv.z *= cw; wv.w *= cw;
                dst[idx] = wv;
            }
        }
    }
    __syncthreads();

    const int o0 = (tid >> 6) * 4;        // wave-uniform -> LDS broadcast reads
    const float* xbase = xT + ((size_t)r0 * B_ + bh * 128 + lane) * I_;

    float acc[4][2];
    #pragma unroll
    for (int oo = 0; oo < 4; ++oo) { acc[oo][0] = 0.f; acc[oo][1] = 0.f; }

    #pragma unroll 2
    for (int r = 0; r < RC_; ++r) {
        const float* xr = xbase + (size_t)r * B_ * I_;
        const float4 a00 = ((const float4*)xr)[0];
        const float4 a01 = ((const float4*)xr)[1];
        const float4 a10 = ((const float4*)(xr + 64 * I_))[0];
        const float4 a11 = ((const float4*)(xr + 64 * I_))[1];
        const float4* wp = (const float4*)&wl[r * 128 + o0 * 8];
        #pragma unroll
        for (int oo = 0; oo < 4; ++oo) {
            const float4 w0 = wp[oo * 2 + 0];
            const float4 w1 = wp[oo * 2 + 1];
            float a = acc[oo][0];
            a = fmaf(a00.x, w0.x, a);
            a = fmaf(a00.y, w0.y, a);
            a = fmaf(a00.z, w0.z, a);
            a = fmaf(a00.w, w0.w, a);
            a = fmaf(a01.x, w1.x, a);
            a = fmaf(a01.y, w1.y, a);
            a = fmaf(a01.z, w1.z, a);
            a = fmaf(a01.w, w1.w, a);
            acc[oo][0] = a;
            float b = acc[oo][1];
            b = fmaf(a10.x, w0.x, b);
            b = fmaf(a10.y, w0.y, b);
            b = fmaf(a10.z, w0.z, b);
            b = fmaf(a10.w, w0.w, b);
            b = fmaf(a11.x, w1.x, b);
            b = fmaf(a11.y, w1.y, b);
            b = fmaf(a11.z, w1.z, b);
            b = fmaf(a11.w, w1.w, b);
            acc[oo][1] = b;
        }
    }

    float* sp = s_dst + (size_t)(c * O_ + o0) * B_ + bh * 128 + lane;
    #pragma unroll
    for (int oo = 0; oo < 4; ++oo) {
        atomicAdd(sp + (size_t)oo * B_, acc[oo][0]);
        atomicAdd(sp + (size_t)oo * B_ + 64, acc[oo][1]);
    }
}

// ===========================================================================
// a8_body<NR>: bij_dst[c, r0+rr] += (1/B) sum_{o,i} W[r,c,o,i] *
//              (sum_b squash(s_read[co][b]) * xT[r,b,i])
// 320 thr = 40 co-QUADS x 8 b-groups of 32.  (r7 a7 was 41 us; this is ~25:)
//  - 4 co per thread: x LDS reads HALVED (128/thr), 16 fma/read.
//  - x LDS XOR-swizzled (e' = e ^ ((e>>6)&7)): killed the 5.97M conflict
//    cycles r7 measured.
//  - squash via v_rcp (was full div sequence, ~38% of VALU).
//  - balanced grid: 384 blocks x 2 routes + 128 x 3 = 512 = 2/CU exactly.
// r9 A/B: 1152-block b-split variant was part of a -6 us regression; kept 512.
// ===========================================================================
struct A8Sh {
    float4 xsw[3 * 512];     // swizzled x, up to 3 routes (24 KB)
    float  part[3][320];     // 3.75 KB
};

template <int NR>
__device__ __forceinline__ void a8_body(int r0, A8Sh& sh,
                                        const float* __restrict__ xT,
                                        const float* __restrict__ Wm,
                                        const float* __restrict__ s_read,
                                        float* __restrict__ bij_dst) {
    const int tid = threadIdx.x;

    // ---- stage x chunk, swizzled: e' = e ^ ((e>>6)&7) (involution) ----
    {
        const float4* src = (const float4*)(xT + (size_t)r0 * B_ * I_);
        for (int k = tid; k < NR * 512; k += 320)
            sh.xsw[k ^ ((k >> 6) & 7)] = src[k];
    }
    __syncthreads();

    const int cq = tid % 40;          // co quad: co = 4cq..4cq+3 (one capsule)
    const int bg = tid / 40;          // 0..7, 32 b each
    const int b0 = bg * 32;

    float acc[NR][4][8];
    #pragma unroll
    for (int rr = 0; rr < NR; ++rr)
        #pragma unroll
        for (int j = 0; j < 4; ++j)
            #pragma unroll
            for (int i = 0; i < 8; ++i) acc[rr][j][i] = 0.f;

    const float* vbase = s_read + (size_t)(4 * cq) * B_ + b0;   // [co][b]

    #pragma unroll 2
    for (int bb = 0; bb < 32; bb += 4) {
        float va[4][4];               // [co j][b j2], squashed
        #pragma unroll
        for (int j = 0; j < 4; ++j) {
            const float4 t = *(const float4*)(vbase + (size_t)j * B_ + bb);
            va[j][0] = squash_fast(t.x);
            va[j][1] = squash_fast(t.y);
            va[j][2] = squash_fast(t.z);
            va[j][3] = squash_fast(t.w);
        }
        #pragma unroll
        for (int j2 = 0; j2 < 4; ++j2) {
            const int eb = (b0 + bb + j2) * 2;
            #pragma unroll
            for (int rr = 0; rr < NR; ++rr) {
                const float4 x0 = sh.xsw[(rr * 512 + eb) ^ bg];
                const float4 x1 = sh.xsw[(rr * 512 + eb + 1) ^ bg];
                #pragma unroll
                for (int j = 0; j < 4; ++j) {
                    const float w = va[j][j2];
                    acc[rr][j][0] = fmaf(w, x0.x, acc[rr][j][0]);
                    acc[rr][j][1] = fmaf(w, x0.y, acc[rr][j][1]);
                    acc[rr][j][2] = fmaf(w, x0.z, acc[rr][j][2]);
                    acc[rr][j][3] = fmaf(w, x0.w, acc[rr][j][3]);
                    acc[rr][j][4] = fmaf(w, x1.x, acc[rr][j][4]);
                    acc[rr][j][5] = fmaf(w, x1.y, acc[rr][j][5]);
                    acc[rr][j][6] = fmaf(w, x1.z, acc[rr][j][6]);
                    acc[rr][j][7] = fmaf(w, x1.w, acc[rr][j][7]);
                }
            }
        }
    }

    // ---- W-dot epilogue: thread's 4 co are within one capsule ----
    #pragma unroll
    for (int rr = 0; rr < NR; ++rr) {
        const float* wp = Wm + (((size_t)(r0 + rr)) * CO_ + 4 * cq) * I_;
        float psum = 0.f;
        #pragma unroll
        for (int j = 0; j < 4; ++j) {
            const float4 w0 = *(const float4*)(wp + j * 8);
            const float4 w1 = *(const float4*)(wp + j * 8 + 4);
            float p = acc[rr][j][0] * w0.x;
            p = fmaf(acc[rr][j][1], w0.y, p);
            p = fmaf(acc[rr][j][2], w0.z, p);
            p = fmaf(acc[rr][j][3], w0.w, p);
            p = fmaf(acc[rr][j][4], w1.x, p);
            p = fmaf(acc[rr][j][5], w1.y, p);
            p = fmaf(acc[rr][j][6], w1.z, p);
            p = fmaf(acc[rr][j][7], w1.w, p);
            psum += p;
        }
        sh.part[rr][tid] = psum;
    }
    __syncthreads();

    // reduce: per (rr, capsule): 8 bg x 4 cq-of-capsule = 32 partials
    if (tid < NR * C_) {
        const int r = tid / C_, c2 = tid % C_;
        float s = 0.f;
        #pragma unroll
        for (int g2 = 0; g2 < 8; ++g2)
            #pragma unroll
            for (int q = 0; q < 4; ++q)
                s += sh.part[r][g2 * 40 + c2 * 4 + q];
        bij_dst[(size_t)c2 * R_ + (r0 + r)] += s * (1.0f / (float)B_);
    }
}

__global__ __launch_bounds__(320) void k_a8(const float* __restrict__ xT,
                                            const float* __restrict__ Wm,
                                            const float* __restrict__ s_read,
                                            float* __restrict__ s_zero,
                                            float* __restrict__ bijT) {
    __shared__ A8Sh sh;
    const int bid = blockIdx.x;
    if (s_zero != nullptr && bid < 40 && threadIdx.x < 256) {
        ((float4*)s_zero)[bid * 256 + threadIdx.x] =
            make_float4(0.f, 0.f, 0.f, 0.f);
    }
    if (bid < NBA2_) {
        a8_body<2>(bid * 2, sh, xT, Wm, s_read, bijT);
    } else {
        a8_body<3>(NBA2_ * 2 + (bid - NBA2_) * 3, sh, xT, Wm, s_read, bijT);
    }
}

// ===========================================================================
// k_sqout: out[b,co] = squash(s[co][b]).  grid 160 (=co), 256 thr (=b).
// ===========================================================================
__global__ __launch_bounds__(256) void k_sqout(const float* __restrict__ s,
                                               float* __restrict__ out) {
    const int co = blockIdx.x;
    const int b  = threadIdx.x;
    out[(size_t)b * CO_ + co] = squash_fast(s[(size_t)co * B_ + b]);
}

// ===========================================================================
// FALLBACK tier 3 (tiny ws)
// ===========================================================================
template <bool UNIFORM>
__global__ __launch_bounds__(256) void k_s_f(const float* __restrict__ x,
                                             const float* __restrict__ Wm,
                                             const float* __restrict__ cij,
                                             float* __restrict__ s_out) {
    const int o  = threadIdx.x & 15;
    const int tb = threadIdx.x >> 4;
    const int b  = blockIdx.z * MBF_ + tb;
    const int c  = blockIdx.y;
    const int r0 = blockIdx.x * RCF_;

    const float* xp = x + ((size_t)b * R_ + r0) * I_;
    const float* wp = Wm + (((size_t)r0 * C_ + c) * O_ + o) * I_;
    const float* cp = cij + (size_t)r0 * C_ + c;

    float acc = 0.f;
    #pragma unroll 4
    for (int r = 0; r < RCF_; ++r) {
        const float4 xv0 = *(const float4*)(xp);
        const float4 xv1 = *(const float4*)(xp + 4);
        const float4 wv0 = *(const float4*)(wp);
        const float4 wv1 = *(const float4*)(wp + 4);
        const float p0 = fmaf(xv0.y, wv0.y, xv0.x * wv0.x);
        const float p1 = fmaf(xv0.w, wv0.w, xv0.z * wv0.z);
        const float p2 = fmaf(xv1.y, wv1.y, xv1.x * wv1.x);
        const float p3 = fmaf(xv1.w, wv1.w, xv1.z * wv1.z);
        const float cw = UNIFORM ? (1.0f / (float)R_) : cp[0];
        acc = fmaf(cw, (p0 + p1) + (p2 + p3), acc);
        xp += I_;
        wp += WRI_;
        cp += C_;
    }
    atomicAdd(&s_out[((size_t)b * C_ + c) * O_ + o], acc);
}

__global__ __launch_bounds__(256) void k_a_f(const float* __restrict__ x,
                                             const float* __restrict__ Wm,
                                             const float* __restrict__ s_in,
                                             float* __restrict__ amean) {
    __shared__ __align__(16) float wlds[2 * WRI_];
    __shared__ float red[4][2 * C_];

    const int tid = threadIdx.x;
    const int r0  = blockIdx.x * 2;

    const float* wsrc = Wm + (size_t)r0 * WRI_;
    #pragma unroll
    for (int k = 0; k < 2 * WRI_ / 256; ++k)
        wlds[tid + 256 * k] = wsrc[tid + 256 * k];
    __syncthreads();

    const int b    = tid;
    const int lane = tid & 63;
    const int wv   = tid >> 6;

    float xv[2][I_];
    const float4* xp4 = (const float4*)(x + ((size_t)b * R_ + r0) * I_);
    #pragma unroll
    for (int rr = 0; rr < 2; ++rr) {
        const float4 a0 = xp4[rr * 2 + 0];
        const float4 a1 = xp4[rr * 2 + 1];
        xv[rr][0] = a0.x; xv[rr][1] = a0.y; xv[rr][2] = a0.z; xv[rr][3] = a0.w;
        xv[rr][4] = a1.x; xv[rr][5] = a1.y; xv[rr][6] = a1.z; xv[rr][7] = a1.w;
    }

    #pragma unroll 1
    for (int c = 0; c < C_; ++c) {
        const float4* sp4 = (const float4*)(s_in + ((size_t)b * C_ + c) * O_);
        float v[O_];
        #pragma unroll
        for (int q = 0; q < 4; ++q) {
            const float4 sv = sp4[q];
            v[q * 4 + 0] = squashf(sv.x);
            v[q * 4 + 1] = squashf(sv.y);
            v[q * 4 + 2] = squashf(sv.z);
            v[q * 4 + 3] = squashf(sv.w);
        }
        #pragma unroll 1
        for (int rr = 0; rr < 2; ++rr) {
            const float4* wl4 = (const float4*)&wlds[(rr * C_ + c) * O_ * I_];
            float a = 0.f;
            #pragma unroll
            for (int o = 0; o < O_; ++o) {
                const float4 w0 = wl4[o * 2 + 0];
                const float4 w1 = wl4[o * 2 + 1];
                float u = xv[rr][0] * w0.x;
                u = fmaf(xv[rr][1], w0.y, u);
                u = fmaf(xv[rr][2], w0.z, u);
                u = fmaf(xv[rr][3], w0.w, u);
                u = fmaf(xv[rr][4], w1.x, u);
                u = fmaf(xv[rr][5], w1.y, u);
                u = fmaf(xv[rr][6], w1.z, u);
                u = fmaf(xv[rr][7], w1.w, u);
                a = fmaf(u, v[o], a);
            }
            #pragma unroll
            for (int off = 32; off > 0; off >>= 1)
                a += __shfl_down(a, off, 64);
            if (lane == 0) red[wv][rr * C_ + c] = a;
        }
    }

    __syncthreads();
    if (tid < 2 * C_) {
        const float t = red[0][tid] + red[1][tid] + red[2][tid] + red[3][tid];
        const int rr = tid / C_;
        const int c  = tid % C_;
        amean[(size_t)(r0 + rr) * C_ + c] = t * (1.0f / (float)B_);
    }
}

__global__ __launch_bounds__(256) void k_soft(const float* __restrict__ amean,
                                              float* __restrict__ bij,
                                              float* __restrict__ cij) {
    const int c   = blockIdx.x;
    const int tid = threadIdx.x;
    __shared__ float sred[4];

    float vals[5];
    float m = -1e30f;
    #pragma unroll
    for (int k = 0; k < 5; ++k) {
        const int r = tid + 256 * k;
        if (r < R_) {
            const size_t idx = (size_t)r * C_ + c;
            const float vv = bij[idx] + amean[idx];
            bij[idx] = vv;
            vals[k] = vv;
            m = fmaxf(m, vv);
        } else {
            vals[k] = -1e30f;
        }
    }
    #pragma unroll
    for (int off = 32; off > 0; off >>= 1)
        m = fmaxf(m, __shfl_down(m, off, 64));
    if ((tid & 63) == 0) sred[tid >> 6] = m;
    __syncthreads();
    const float bm = fmaxf(fmaxf(sred[0], sred[1]), fmaxf(sred[2], sred[3]));
    __syncthreads();

    float se = 0.f;
    #pragma unroll
    for (int k = 0; k < 5; ++k)
        se += (vals[k] > -1e29f) ? expf(vals[k] - bm) : 0.f;
    #pragma unroll
    for (int off = 32; off > 0; off >>= 1)
        se += __shfl_down(se, off, 64);
    if ((tid & 63) == 0) sred[tid >> 6] = se;
    __syncthreads();
    const float inv = 1.0f / (sred[0] + sred[1] + sred[2] + sred[3]);

    #pragma unroll
    for (int k = 0; k < 5; ++k) {
        const int r = tid + 256 * k;
        if (r < R_) cij[(size_t)r * C_ + c] = expf(vals[k] - bm) * inv;
    }
}

__global__ __launch_bounds__(256) void k_squash(float* __restrict__ s) {
    const int idx = blockIdx.x * 256 + threadIdx.x;
    if (idx < B_ * CO_) s[idx] = squashf(s[idx]);
}

} // namespace

extern "C" void kernel_launch(void* const* d_in, const int* in_sizes, int n_in,
                              void* d_out, int out_size, void* d_ws, size_t ws_size,
                              hipStream_t stream) {
    const float* x  = (const float*)d_in[0];   // [256,1152,8]
    const float* Wm = (const float*)d_in[1];   // [1152,10,16,8]
    float* out = (float*)d_out;                // [256,10,16] flat = 40960
    float* ws  = (float*)d_ws;

    const size_t need = FL_TOTAL * sizeof(float);

    if (ws_size >= need) {
        // ---------------- main path: 7 nodes (r8 config, best = 196 us) ----
        float* xT   = ws + XT_OFF;
        float* sA   = ws + SA_OFF;
        float* sB   = ws + SB_OFF;
        float* bijT = ws + BIJ_OFF;

        k_tr<<<1152, 256, 0, stream>>>(x, xT, sA /* = zbase, zeroes sA|sB|bij */);

        // iter 0 (uniform weights; softmax(0) == 1/R)
        k_s8<true><<<C_ * 64, 256, 0, stream>>>(xT, Wm, bijT, sA);
        k_a8<<<NBA_, 320, 0, stream>>>(xT, Wm, sA, nullptr, bijT);

        // iter 1  (sB zeroed by k_tr)
        k_s8<false><<<C_ * 64, 256, 0, stream>>>(xT, Wm, bijT, sB);
        k_a8<<<NBA_, 320, 0, stream>>>(xT, Wm, sB, sA /* zero for iter 2 */, bijT);

        // iter 2
        k_s8<false><<<C_ * 64, 256, 0, stream>>>(xT, Wm, bijT, sA);
        k_sqout<<<CO_, 256, 0, stream>>>(sA, out);
    } else {
        // ---------------- tier 3 ----------------
        float* s_buf = ws;
        float* cij   = ws + 40960;
        float* bij   = cij + R_ * C_;
        float* amean = bij + R_ * C_;

        const dim3 gsf(KSF_, C_, B_ / MBF_);

        hipMemsetAsync(bij, 0, R_ * C_ * sizeof(float), stream);

        hipMemsetAsync(s_buf, 0, B_ * CO_ * sizeof(float), stream);
        k_s_f<true><<<gsf, 256, 0, stream>>>(x, Wm, cij, s_buf);
        k_a_f<<<R_ / 2, 256, 0, stream>>>(x, Wm, s_buf, amean);
        k_soft<<<C_, 256, 0, stream>>>(amean, bij, cij);

        hipMemsetAsync(s_buf, 0, B_ * CO_ * sizeof(float), stream);
        k_s_f<false><<<gsf, 256, 0, stream>>>(x, Wm, cij, s_buf);
        k_a_f<<<R_ / 2, 256, 0, stream>>>(x, Wm, s_buf, amean);
        k_soft<<<C_, 256, 0, stream>>>(amean, bij, cij);

        hipMemsetAsync(out, 0, B_ * CO_ * sizeof(float), stream);
        k_s_f<false><<<gsf, 256, 0, stream>>>(x, Wm, cij, out);
        k_squash<<<(B_ * CO_ + 255) / 256, 256, 0, stream>>>(out);
    }
}

// Round 11
// 177.072 us; speedup vs baseline: 1.1407x; 1.1015x over previous
//
#include <hip/hip_runtime.h>
#include <math.h>

namespace {

constexpr int B_ = 256;
constexpr int R_ = 1152;
constexpr int C_ = 10;
constexpr int O_ = 16;
constexpr int I_ = 8;
constexpr int CO_ = C_ * O_;          // 160
constexpr int WRI_ = C_ * O_ * I_;    // 1280 floats of W per route

constexpr int KS_  = 64;              // r-splits in s-phase
constexpr int RC_  = R_ / KS_;        // 18 routes per s-block

// fallback tier-3 params
constexpr int KSF_ = 16;
constexpr int RCF_ = R_ / KSF_;       // 72
constexpr int MBF_ = 16;

// ws layout (float offsets) — sA|sB|bij contiguous so k_tr zeroes one range
constexpr size_t XT_OFF    = 0;                          // [R][B][I]
constexpr size_t XT_N      = (size_t)R_ * B_ * I_;       // 2,359,296
constexpr size_t SA_OFF    = XT_OFF + XT_N;              // [CO][B] raw s, iter 0/2
constexpr size_t SAB_N     = (size_t)CO_ * B_;           // 40,960
constexpr size_t SB_OFF    = SA_OFF + SAB_N;             // [CO][B] raw s, iter 1
constexpr size_t BIJ_OFF   = SB_OFF + SAB_N;             // [C][R]
constexpr size_t BIJ_N     = (size_t)C_ * R_;            // 11,520
constexpr size_t ZERO_N    = 2 * SAB_N + BIJ_N;          // 93,440 floats
constexpr size_t VT_OFF    = BIJ_OFF + BIJ_N;            // [B][CO] squashed v
constexpr size_t VT_N      = (size_t)B_ * CO_;           // 40,960
constexpr size_t FL_TOTAL  = VT_OFF + VT_N;

__device__ __forceinline__ float rcp_fast(float x) {
#if defined(__has_builtin)
#if __has_builtin(__builtin_amdgcn_rcpf)
    return __builtin_amdgcn_rcpf(x);   // v_rcp_f32, ~1 ulp
#else
    return 1.0f / x;
#endif
#else
    return 1.0f / x;
#endif
}

__device__ __forceinline__ float squashf(float s) {
    // faithful to reference: s^2*s/((1+s^2)*sqrt(s^2)) == s*|s|/(1+s^2)
    return s * fabsf(s) / (1.0f + s * s);
}

// fast variant: v_rcp instead of full div sequence.
__device__ __forceinline__ float squash_fast(float s) {
    return s * fabsf(s) * rcp_fast(1.0f + s * s);
}

// ===========================================================================
// k_tr: x[b,r,i] -> xT[r,b,i]; zero sA|sB|bij.  tile 8 b x 32 r.  grid 1152.
// ===========================================================================
__global__ __launch_bounds__(256) void k_tr(const float* __restrict__ x,
                                            float* __restrict__ xT,
                                            float* __restrict__ zbase) {
    __shared__ float t[8][32][8];
    const int tid = threadIdx.x;
    {
        const int gi = blockIdx.x * 256 + tid;
        if (gi < (int)(ZERO_N / 4))
            ((float4*)zbase)[gi] = make_float4(0.f, 0.f, 0.f, 0.f);
    }
    const int r0 = (blockIdx.x % 36) * 32;
    const int b0 = (blockIdx.x / 36) * 8;
    {
        const int rl = tid & 31, bl = tid >> 5;
        const float4* p = (const float4*)(x + ((size_t)(b0 + bl) * R_ + (r0 + rl)) * I_);
        const float4 a0 = p[0], a1 = p[1];
        float* d = &t[bl][rl][0];
        *(float4*)d = a0;
        *(float4*)(d + 4) = a1;
    }
    __syncthreads();
    {
        const int f = tid & 7, rw = tid >> 3;   // f = b-local
        const float* s8 = &t[f][rw][0];
        const float4 a0 = *(const float4*)s8, a1 = *(const float4*)(s8 + 4);
        float* d = xT + ((size_t)(r0 + rw) * B_ + (b0 + f)) * I_;
        *(float4*)d = a0;
        *(float4*)(d + 4) = a1;
    }
}

// ===========================================================================
// k_s9: s_dst[co][b] (+=, atomic) sum_{r in 18-chunk} cw[r,c] *
//       dot(W[r,c,o,:], xT[r,b,:])
// grid 640: bid = c*64 + ks.  c-stride 64 == 0 (mod 8): all 10 c-copies of
// an x-chunk land on one XCD (L2 reuse).
// NB=4 (full batch per block): the 8 W-broadcast b128 reads per r amortize
// over 128 fma (was 64 at NB=2).  r10 math: s8 was LDS-pipe-bound
// (~34.5K LDS cyc/CU ~= its whole 13 us); NB=4 halves per-CU LDS work.
// ===========================================================================
template <bool UNIFORM>
__global__ __launch_bounds__(256) void k_s9(const float* __restrict__ xT,
                                            const float* __restrict__ Wm,
                                            const float* __restrict__ bijT,
                                            float* __restrict__ s_dst) {
    __shared__ __align__(16) float wl[RC_ * 128];   // 9.2 KB
    __shared__ float cwch[RC_];
    __shared__ float sred[8];

    const int tid  = threadIdx.x;
    const int lane = tid & 63;
    const int bid  = blockIdx.x;
    const int c    = bid >> 6;            // 0..9
    const int ks   = bid & 63;            // 0..63
    const int r0   = ks * RC_;

    // ---- per-block softmax over routes for capsule c -> cwch[0..17] ----
    if (!UNIFORM) {
        const float* bc = bijT + (size_t)c * R_;
        float bv[5];
        float m = -1e30f;
        #pragma unroll
        for (int k = 0; k < 5; ++k) {
            const int r = tid + 256 * k;
            bv[k] = (r < R_) ? bc[r] : -1e30f;
            m = fmaxf(m, bv[k]);
        }
        #pragma unroll
        for (int off = 32; off > 0; off >>= 1)
            m = fmaxf(m, __shfl_down(m, off, 64));
        if (lane == 0) sred[tid >> 6] = m;
        __syncthreads();
        const float bm = fmaxf(fmaxf(sred[0], sred[1]), fmaxf(sred[2], sred[3]));
        float se = 0.f;
        #pragma unroll
        for (int k = 0; k < 5; ++k)
            se += (bv[k] > -1e29f) ? expf(bv[k] - bm) : 0.f;
        #pragma unroll
        for (int off = 32; off > 0; off >>= 1)
            se += __shfl_down(se, off, 64);
        if (lane == 0) sred[4 + (tid >> 6)] = se;
        __syncthreads();
        const float inv = 1.0f / (sred[4] + sred[5] + sred[6] + sred[7]);
        if (tid < RC_) cwch[tid] = expf(bc[r0 + tid] - bm) * inv;
        __syncthreads();
    }

    // ---- stage cw-scaled W chunk: 18 r x 32 f4 = 576 f4 ----
    {
        const float4* src = (const float4*)(Wm + ((size_t)r0 * C_ + c) * 128);
        float4* dst = (float4*)wl;
        #pragma unroll
        for (int k = 0; k < (RC_ * 32 + 255) / 256; ++k) {
            const int idx = tid + 256 * k;
            if (idx < RC_ * 32) {
                const int r = idx >> 5, q = idx & 31;
                float4 wv = src[(size_t)r * (C_ * 32) + q];
                const float cw = UNIFORM ? (1.0f / (float)R_) : cwch[r];
                wv.x *= cw; wv.y *= cw; wv.z *= cw; wv.w *= cw;
                dst[idx] = wv;
            }
        }
    }
    __syncthreads();

    const int o0 = (tid >> 6) * 4;        // wave-uniform -> LDS broadcast reads
    const float* xbase = xT + ((size_t)r0 * B_ + lane) * I_;

    float acc[4][4];                      // [oo][bb]
    #pragma unroll
    for (int oo = 0; oo < 4; ++oo)
        #pragma unroll
        for (int bb = 0; bb < 4; ++bb) acc[oo][bb] = 0.f;

    #pragma unroll 2
    for (int r = 0; r < RC_; ++r) {
        const float* xr = xbase + (size_t)r * B_ * I_;
        float4 xa[4][2];
        #pragma unroll
        for (int bb = 0; bb < 4; ++bb) {
            const float4* xp = (const float4*)(xr + (size_t)bb * 64 * I_);
            xa[bb][0] = xp[0];
            xa[bb][1] = xp[1];
        }
        const float4* wp = (const float4*)&wl[r * 128 + o0 * 8];
        #pragma unroll
        for (int oo = 0; oo < 4; ++oo) {
            const float4 w0 = wp[oo * 2 + 0];
            const float4 w1 = wp[oo * 2 + 1];
            #pragma unroll
            for (int bb = 0; bb < 4; ++bb) {
                float a = acc[oo][bb];
                a = fmaf(xa[bb][0].x, w0.x, a);
                a = fmaf(xa[bb][0].y, w0.y, a);
                a = fmaf(xa[bb][0].z, w0.z, a);
                a = fmaf(xa[bb][0].w, w0.w, a);
                a = fmaf(xa[bb][1].x, w1.x, a);
                a = fmaf(xa[bb][1].y, w1.y, a);
                a = fmaf(xa[bb][1].z, w1.z, a);
                a = fmaf(xa[bb][1].w, w1.w, a);
                acc[oo][bb] = a;
            }
        }
    }

    float* sp = s_dst + (size_t)(c * O_ + o0) * B_ + lane;
    #pragma unroll
    for (int oo = 0; oo < 4; ++oo)
        #pragma unroll
        for (int bb = 0; bb < 4; ++bb)
            atomicAdd(sp + (size_t)oo * B_ + bb * 64, acc[oo][bb]);
}

// ===========================================================================
// k_vt: vT[b][co] = squash(s[co][b]).  Transpose+squash so the a-kernel's
// per-thread 4-co read becomes ONE coalesced float4 (r10 counters: the
// [co][b] layout scattered every a-kernel v-load across ~64 cache lines).
// grid 20 = 5 co-tiles(32) x 4 b-tiles(64), 256 thr.
// ===========================================================================
__global__ __launch_bounds__(256) void k_vt(const float* __restrict__ s,
                                            float* __restrict__ vT) {
    __shared__ float t[32][65];
    const int tid  = threadIdx.x;
    const int co0  = (blockIdx.x % 5) * 32;
    const int b0   = (blockIdx.x / 5) * 64;
    const int lane = tid & 63;
    const int g    = tid >> 6;            // 0..3
    #pragma unroll
    for (int k = 0; k < 8; ++k) {
        const int co = g + k * 4;
        t[co][lane] = s[(size_t)(co0 + co) * B_ + b0 + lane];
    }
    __syncthreads();
    const int bl  = tid >> 2;             // 0..63
    const int coq = (tid & 3) * 8;        // 0,8,16,24
    float* dst = vT + (size_t)(b0 + bl) * CO_ + co0 + coq;
    float4 o0, o1;
    o0.x = squash_fast(t[coq + 0][bl]);
    o0.y = squash_fast(t[coq + 1][bl]);
    o0.z = squash_fast(t[coq + 2][bl]);
    o0.w = squash_fast(t[coq + 3][bl]);
    o1.x = squash_fast(t[coq + 4][bl]);
    o1.y = squash_fast(t[coq + 5][bl]);
    o1.z = squash_fast(t[coq + 6][bl]);
    o1.w = squash_fast(t[coq + 7][bl]);
    *(float4*)dst = o0;
    *(float4*)(dst + 4) = o1;
}

// ===========================================================================
// k_a10: bijT[c][r] += (1/B) sum_{o,i} W[r,c,o,i] *
//        (sum_b vT[b][co] * xT[r,b,i])
// grid 1152 = ONE ROUTE PER BLOCK (uniform, 4.5 blocks/CU fully resident —
// r10 counters showed a8's 2/3-route grid ran a 1.5x tail at 10% occupancy).
// 320 thr = 40 co-quads x 8 b-groups of 32.  v reads: one coalesced f4 per
// (b, co-quad) from vT (pre-squashed by k_vt).  x in swizzled LDS (8 KB).
// bij single-writer per r -> plain += (no atomics).
// ===========================================================================
struct A10Sh {
    float4 xsw[512];         // swizzled x: 256 b x 8 i (8 KB)
    float  part[320];
};

__global__ __launch_bounds__(320) void k_a10(const float* __restrict__ xT,
                                             const float* __restrict__ Wm,
                                             const float* __restrict__ vT,
                                             float* __restrict__ s_zero,
                                             float* __restrict__ bijT) {
    __shared__ A10Sh sh;
    const int tid = threadIdx.x;
    const int r   = blockIdx.x;

    if (s_zero != nullptr && r < 40 && tid < 256) {
        ((float4*)s_zero)[r * 256 + tid] = make_float4(0.f, 0.f, 0.f, 0.f);
    }

    // ---- stage x[r], swizzled: slot = k ^ ((k>>6)&7); k = 2b+ih ----
    {
        const float4* src = (const float4*)(xT + (size_t)r * B_ * I_);
        for (int k = tid; k < 512; k += 320)
            sh.xsw[k ^ ((k >> 6) & 7)] = src[k];
    }
    __syncthreads();

    const int cq = tid % 40;          // co quad: co = 4cq..4cq+3 (one capsule)
    const int bg = tid / 40;          // 0..7, 32 b each
    const int b0 = bg * 32;

    float acc[4][8];
    #pragma unroll
    for (int j = 0; j < 4; ++j)
        #pragma unroll
        for (int i = 0; i < 8; ++i) acc[j][i] = 0.f;

    const float* vb = vT + (size_t)b0 * CO_ + 4 * cq;

    #pragma unroll 2
    for (int bb = 0; bb < 32; bb += 4) {
        float va[4][4];               // [b j2][co j]
        #pragma unroll
        for (int j2 = 0; j2 < 4; ++j2) {
            const float4 t = *(const float4*)(vb + (size_t)(bb + j2) * CO_);
            va[j2][0] = t.x; va[j2][1] = t.y; va[j2][2] = t.z; va[j2][3] = t.w;
        }
        #pragma unroll
        for (int j2 = 0; j2 < 4; ++j2) {
            const int e0 = ((b0 + bb + j2) * 2) ^ bg;
            const float4 x0 = sh.xsw[e0];
            const float4 x1 = sh.xsw[e0 ^ 1];
            #pragma unroll
            for (int j = 0; j < 4; ++j) {
                const float w = va[j2][j];
                acc[j][0] = fmaf(w, x0.x, acc[j][0]);
                acc[j][1] = fmaf(w, x0.y, acc[j][1]);
                acc[j][2] = fmaf(w, x0.z, acc[j][2]);
                acc[j][3] = fmaf(w, x0.w, acc[j][3]);
                acc[j][4] = fmaf(w, x1.x, acc[j][4]);
                acc[j][5] = fmaf(w, x1.y, acc[j][5]);
                acc[j][6] = fmaf(w, x1.z, acc[j][6]);
                acc[j][7] = fmaf(w, x1.w, acc[j][7]);
            }
        }
    }

    // ---- W-dot epilogue: thread's 4 co are within one capsule ----
    {
        const float* wp = Wm + ((size_t)r * CO_ + 4 * cq) * I_;
        float psum = 0.f;
        #pragma unroll
        for (int j = 0; j < 4; ++j) {
            const float4 w0 = *(const float4*)(wp + j * 8);
            const float4 w1 = *(const float4*)(wp + j * 8 + 4);
            float p = acc[j][0] * w0.x;
            p = fmaf(acc[j][1], w0.y, p);
            p = fmaf(acc[j][2], w0.z, p);
            p = fmaf(acc[j][3], w0.w, p);
            p = fmaf(acc[j][4], w1.x, p);
            p = fmaf(acc[j][5], w1.y, p);
            p = fmaf(acc[j][6], w1.z, p);
            p = fmaf(acc[j][7], w1.w, p);
            psum += p;
        }
        sh.part[tid] = psum;
    }
    __syncthreads();

    // reduce per capsule: 8 bg x 4 cq-of-capsule = 32 partials
    if (tid < C_) {
        float s = 0.f;
        #pragma unroll
        for (int g2 = 0; g2 < 8; ++g2)
            #pragma unroll
            for (int q = 0; q < 4; ++q)
                s += sh.part[g2 * 40 + tid * 4 + q];
        bijT[(size_t)tid * R_ + r] += s * (1.0f / (float)B_);
    }
}

// ===========================================================================
// k_sqout: out[b,co] = squash(s[co][b]).  grid 160 (=co), 256 thr (=b).
// ===========================================================================
__global__ __launch_bounds__(256) void k_sqout(const float* __restrict__ s,
                                               float* __restrict__ out) {
    const int co = blockIdx.x;
    const int b  = threadIdx.x;
    out[(size_t)b * CO_ + co] = squash_fast(s[(size_t)co * B_ + b]);
}

// ===========================================================================
// FALLBACK tier 3 (tiny ws)
// ===========================================================================
template <bool UNIFORM>
__global__ __launch_bounds__(256) void k_s_f(const float* __restrict__ x,
                                             const float* __restrict__ Wm,
                                             const float* __restrict__ cij,
                                             float* __restrict__ s_out) {
    const int o  = threadIdx.x & 15;
    const int tb = threadIdx.x >> 4;
    const int b  = blockIdx.z * MBF_ + tb;
    const int c  = blockIdx.y;
    const int r0 = blockIdx.x * RCF_;

    const float* xp = x + ((size_t)b * R_ + r0) * I_;
    const float* wp = Wm + (((size_t)r0 * C_ + c) * O_ + o) * I_;
    const float* cp = cij + (size_t)r0 * C_ + c;

    float acc = 0.f;
    #pragma unroll 4
    for (int r = 0; r < RCF_; ++r) {
        const float4 xv0 = *(const float4*)(xp);
        const float4 xv1 = *(const float4*)(xp + 4);
        const float4 wv0 = *(const float4*)(wp);
        const float4 wv1 = *(const float4*)(wp + 4);
        const float p0 = fmaf(xv0.y, wv0.y, xv0.x * wv0.x);
        const float p1 = fmaf(xv0.w, wv0.w, xv0.z * wv0.z);
        const float p2 = fmaf(xv1.y, wv1.y, xv1.x * wv1.x);
        const float p3 = fmaf(xv1.w, wv1.w, xv1.z * wv1.z);
        const float cw = UNIFORM ? (1.0f / (float)R_) : cp[0];
        acc = fmaf(cw, (p0 + p1) + (p2 + p3), acc);
        xp += I_;
        wp += WRI_;
        cp += C_;
    }
    atomicAdd(&s_out[((size_t)b * C_ + c) * O_ + o], acc);
}

__global__ __launch_bounds__(256) void k_a_f(const float* __restrict__ x,
                                             const float* __restrict__ Wm,
                                             const float* __restrict__ s_in,
                                             float* __restrict__ amean) {
    __shared__ __align__(16) float wlds[2 * WRI_];
    __shared__ float red[4][2 * C_];

    const int tid = threadIdx.x;
    const int r0  = blockIdx.x * 2;

    const float* wsrc = Wm + (size_t)r0 * WRI_;
    #pragma unroll
    for (int k = 0; k < 2 * WRI_ / 256; ++k)
        wlds[tid + 256 * k] = wsrc[tid + 256 * k];
    __syncthreads();

    const int b    = tid;
    const int lane = tid & 63;
    const int wv   = tid >> 6;

    float xv[2][I_];
    const float4* xp4 = (const float4*)(x + ((size_t)b * R_ + r0) * I_);
    #pragma unroll
    for (int rr = 0; rr < 2; ++rr) {
        const float4 a0 = xp4[rr * 2 + 0];
        const float4 a1 = xp4[rr * 2 + 1];
        xv[rr][0] = a0.x; xv[rr][1] = a0.y; xv[rr][2] = a0.z; xv[rr][3] = a0.w;
        xv[rr][4] = a1.x; xv[rr][5] = a1.y; xv[rr][6] = a1.z; xv[rr][7] = a1.w;
    }

    #pragma unroll 1
    for (int c = 0; c < C_; ++c) {
        const float4* sp4 = (const float4*)(s_in + ((size_t)b * C_ + c) * O_);
        float v[O_];
        #pragma unroll
        for (int q = 0; q < 4; ++q) {
            const float4 sv = sp4[q];
            v[q * 4 + 0] = squashf(sv.x);
            v[q * 4 + 1] = squashf(sv.y);
            v[q * 4 + 2] = squashf(sv.z);
            v[q * 4 + 3] = squashf(sv.w);
        }
        #pragma unroll 1
        for (int rr = 0; rr < 2; ++rr) {
            const float4* wl4 = (const float4*)&wlds[(rr * C_ + c) * O_ * I_];
            float a = 0.f;
            #pragma unroll
            for (int o = 0; o < O_; ++o) {
                const float4 w0 = wl4[o * 2 + 0];
                const float4 w1 = wl4[o * 2 + 1];
                float u = xv[rr][0] * w0.x;
                u = fmaf(xv[rr][1], w0.y, u);
                u = fmaf(xv[rr][2], w0.z, u);
                u = fmaf(xv[rr][3], w0.w, u);
                u = fmaf(xv[rr][4], w1.x, u);
                u = fmaf(xv[rr][5], w1.y, u);
                u = fmaf(xv[rr][6], w1.z, u);
                u = fmaf(xv[rr][7], w1.w, u);
                a = fmaf(u, v[o], a);
            }
            #pragma unroll
            for (int off = 32; off > 0; off >>= 1)
                a += __shfl_down(a, off, 64);
            if (lane == 0) red[wv][rr * C_ + c] = a;
        }
    }

    __syncthreads();
    if (tid < 2 * C_) {
        const float t = red[0][tid] + red[1][tid] + red[2][tid] + red[3][tid];
        const int rr = tid / C_;
        const int c  = tid % C_;
        amean[(size_t)(r0 + rr) * C_ + c] = t * (1.0f / (float)B_);
    }
}

__global__ __launch_bounds__(256) void k_soft(const float* __restrict__ amean,
                                              float* __restrict__ bij,
                                              float* __restrict__ cij) {
    const int c   = blockIdx.x;
    const int tid = threadIdx.x;
    __shared__ float sred[4];

    float vals[5];
    float m = -1e30f;
    #pragma unroll
    for (int k = 0; k < 5; ++k) {
        const int r = tid + 256 * k;
        if (r < R_) {
            const size_t idx = (size_t)r * C_ + c;
            const float vv = bij[idx] + amean[idx];
            bij[idx] = vv;
            vals[k] = vv;
            m = fmaxf(m, vv);
        } else {
            vals[k] = -1e30f;
        }
    }
    #pragma unroll
    for (int off = 32; off > 0; off >>= 1)
        m = fmaxf(m, __shfl_down(m, off, 64));
    if ((tid & 63) == 0) sred[tid >> 6] = m;
    __syncthreads();
    const float bm = fmaxf(fmaxf(sred[0], sred[1]), fmaxf(sred[2], sred[3]));
    __syncthreads();

    float se = 0.f;
    #pragma unroll
    for (int k = 0; k < 5; ++k)
        se += (vals[k] > -1e29f) ? expf(vals[k] - bm) : 0.f;
    #pragma unroll
    for (int off = 32; off > 0; off >>= 1)
        se += __shfl_down(se, off, 64);
    if ((tid & 63) == 0) sred[tid >> 6] = se;
    __syncthreads();
    const float inv = 1.0f / (sred[0] + sred[1] + sred[2] + sred[3]);

    #pragma unroll
    for (int k = 0; k < 5; ++k) {
        const int r = tid + 256 * k;
        if (r < R_) cij[(size_t)r * C_ + c] = expf(vals[k] - bm) * inv;
    }
}

__global__ __launch_bounds__(256) void k_squash(float* __restrict__ s) {
    const int idx = blockIdx.x * 256 + threadIdx.x;
    if (idx < B_ * CO_) s[idx] = squashf(s[idx]);
}

} // namespace

extern "C" void kernel_launch(void* const* d_in, const int* in_sizes, int n_in,
                              void* d_out, int out_size, void* d_ws, size_t ws_size,
                              hipStream_t stream) {
    const float* x  = (const float*)d_in[0];   // [256,1152,8]
    const float* Wm = (const float*)d_in[1];   // [1152,10,16,8]
    float* out = (float*)d_out;                // [256,10,16] flat = 40960
    float* ws  = (float*)d_ws;

    const size_t need = FL_TOTAL * sizeof(float);

    if (ws_size >= need) {
        // ---------------- main path: 9 nodes ----------------
        float* xT   = ws + XT_OFF;
        float* sA   = ws + SA_OFF;
        float* sB   = ws + SB_OFF;
        float* bijT = ws + BIJ_OFF;
        float* vTb  = ws + VT_OFF;

        k_tr<<<1152, 256, 0, stream>>>(x, xT, sA /* = zbase, zeroes sA|sB|bij */);

        // iter 0 (uniform weights; softmax(0) == 1/R)
        k_s9<true><<<C_ * KS_, 256, 0, stream>>>(xT, Wm, bijT, sA);
        k_vt<<<20, 256, 0, stream>>>(sA, vTb);
        k_a10<<<R_, 320, 0, stream>>>(xT, Wm, vTb, nullptr, bijT);

        // iter 1  (sB zeroed by k_tr)
        k_s9<false><<<C_ * KS_, 256, 0, stream>>>(xT, Wm, bijT, sB);
        k_vt<<<20, 256, 0, stream>>>(sB, vTb);
        k_a10<<<R_, 320, 0, stream>>>(xT, Wm, vTb, sA /* zero for iter 2 */, bijT);

        // iter 2
        k_s9<false><<<C_ * KS_, 256, 0, stream>>>(xT, Wm, bijT, sA);
        k_sqout<<<CO_, 256, 0, stream>>>(sA, out);
    } else {
        // ---------------- tier 3 ----------------
        float* s_buf = ws;
        float* cij   = ws + 40960;
        float* bij   = cij + R_ * C_;
        float* amean = bij + R_ * C_;

        const dim3 gsf(KSF_, C_, B_ / MBF_);

        hipMemsetAsync(bij, 0, R_ * C_ * sizeof(float), stream);

        hipMemsetAsync(s_buf, 0, B_ * CO_ * sizeof(float), stream);
        k_s_f<true><<<gsf, 256, 0, stream>>>(x, Wm, cij, s_buf);
        k_a_f<<<R_ / 2, 256, 0, stream>>>(x, Wm, s_buf, amean);
        k_soft<<<C_, 256, 0, stream>>>(amean, bij, cij);

        hipMemsetAsync(s_buf, 0, B_ * CO_ * sizeof(float), stream);
        k_s_f<false><<<gsf, 256, 0, stream>>>(x, Wm, cij, s_buf);
        k_a_f<<<R_ / 2, 256, 0, stream>>>(x, Wm, s_buf, amean);
        k_soft<<<C_, 256, 0, stream>>>(amean, bij, cij);

        hipMemsetAsync(out, 0, B_ * CO_ * sizeof(float), stream);
        k_s_f<false><<<gsf, 256, 0, stream>>>(x, Wm, cij, out);
        k_squash<<<(B_ * CO_ + 255) / 256, 256, 0, stream>>>(out);
    }
}

// Round 12
// 168.650 us; speedup vs baseline: 1.1976x; 1.0499x over previous
//
#include <hip/hip_runtime.h>
#include <math.h>

namespace {

// ===========================================================================
// DigitCaps routing, final configuration (session best: 177 us, round 11).
//
// Structure: 9 serial kernels —
//   k_tr (transpose x + zero buffers)
//   3x k_s9 (softmax-weighted s-accumulation, XCD-local x reuse)
//   2x k_vt (squash + transpose s -> vT for coalesced a-phase reads)
//   2x k_a10 (agreement update, 1 route/block uniform grid)
//   k_sqout (final squash -> out)
//
// Session findings baked in (each counter-verified):
//  - bank-conflict XOR swizzle on a-phase x LDS   (r7: 5.97M cyc -> 10K)
//  - v_rcp squash (div was ~38% of a-phase VALU, r7)
//  - uniform 1-route a-grid (r10: 2/3-route grid ran a 1.5x tail @10% occ)
//  - vT pre-squash/transpose (r10: [co][b] scatter -> coalesced f4 reads)
//  - NB=4 s-kernel (W-broadcast LDS reads amortized over 128 fma)
//  - XCD-aware s-grid (c-stride % 8 == 0 keeps 10 c-copies on one XCD)
// Falsified levers (do not revisit): global/L2 traffic staging (r1),
// monolithic cooperative fusion (r2: 3x slower), launch count (r6),
// device-scope fences per block (r4: 116 us/kernel), grid-doubling (r9).
//
// Residual: ~44 us harness ws-poison fill + ~50 us serial launch chain +
// latency floor at I=8 arithmetic intensity. Not counter-addressable.
// ===========================================================================

constexpr int B_ = 256;
constexpr int R_ = 1152;
constexpr int C_ = 10;
constexpr int O_ = 16;
constexpr int I_ = 8;
constexpr int CO_ = C_ * O_;          // 160
constexpr int WRI_ = C_ * O_ * I_;    // 1280 floats of W per route

constexpr int KS_  = 64;              // r-splits in s-phase
constexpr int RC_  = R_ / KS_;        // 18 routes per s-block

// fallback tier-3 params
constexpr int KSF_ = 16;
constexpr int RCF_ = R_ / KSF_;       // 72
constexpr int MBF_ = 16;

// ws layout (float offsets) — sA|sB|bij contiguous so k_tr zeroes one range
constexpr size_t XT_OFF    = 0;                          // [R][B][I]
constexpr size_t XT_N      = (size_t)R_ * B_ * I_;       // 2,359,296
constexpr size_t SA_OFF    = XT_OFF + XT_N;              // [CO][B] raw s, iter 0/2
constexpr size_t SAB_N     = (size_t)CO_ * B_;           // 40,960
constexpr size_t SB_OFF    = SA_OFF + SAB_N;             // [CO][B] raw s, iter 1
constexpr size_t BIJ_OFF   = SB_OFF + SAB_N;             // [C][R]
constexpr size_t BIJ_N     = (size_t)C_ * R_;            // 11,520
constexpr size_t ZERO_N    = 2 * SAB_N + BIJ_N;          // 93,440 floats
constexpr size_t VT_OFF    = BIJ_OFF + BIJ_N;            // [B][CO] squashed v
constexpr size_t VT_N      = (size_t)B_ * CO_;           // 40,960
constexpr size_t FL_TOTAL  = VT_OFF + VT_N;

__device__ __forceinline__ float rcp_fast(float x) {
#if defined(__has_builtin)
#if __has_builtin(__builtin_amdgcn_rcpf)
    return __builtin_amdgcn_rcpf(x);   // v_rcp_f32, ~1 ulp
#else
    return 1.0f / x;
#endif
#else
    return 1.0f / x;
#endif
}

__device__ __forceinline__ float squashf(float s) {
    // faithful to reference: s^2*s/((1+s^2)*sqrt(s^2)) == s*|s|/(1+s^2)
    return s * fabsf(s) / (1.0f + s * s);
}

// fast variant: v_rcp instead of full div sequence.
__device__ __forceinline__ float squash_fast(float s) {
    return s * fabsf(s) * rcp_fast(1.0f + s * s);
}

// ===========================================================================
// k_tr: x[b,r,i] -> xT[r,b,i]; zero sA|sB|bij.  tile 8 b x 32 r.  grid 1152.
// ===========================================================================
__global__ __launch_bounds__(256) void k_tr(const float* __restrict__ x,
                                            float* __restrict__ xT,
                                            float* __restrict__ zbase) {
    __shared__ float t[8][32][8];
    const int tid = threadIdx.x;
    {
        const int gi = blockIdx.x * 256 + tid;
        if (gi < (int)(ZERO_N / 4))
            ((float4*)zbase)[gi] = make_float4(0.f, 0.f, 0.f, 0.f);
    }
    const int r0 = (blockIdx.x % 36) * 32;
    const int b0 = (blockIdx.x / 36) * 8;
    {
        const int rl = tid & 31, bl = tid >> 5;
        const float4* p = (const float4*)(x + ((size_t)(b0 + bl) * R_ + (r0 + rl)) * I_);
        const float4 a0 = p[0], a1 = p[1];
        float* d = &t[bl][rl][0];
        *(float4*)d = a0;
        *(float4*)(d + 4) = a1;
    }
    __syncthreads();
    {
        const int f = tid & 7, rw = tid >> 3;   // f = b-local
        const float* s8 = &t[f][rw][0];
        const float4 a0 = *(const float4*)s8, a1 = *(const float4*)(s8 + 4);
        float* d = xT + ((size_t)(r0 + rw) * B_ + (b0 + f)) * I_;
        *(float4*)d = a0;
        *(float4*)(d + 4) = a1;
    }
}

// ===========================================================================
// k_s9: s_dst[co][b] (+=, atomic) sum_{r in 18-chunk} cw[r,c] *
//       dot(W[r,c,o,:], xT[r,b,:])
// grid 640: bid = c*64 + ks.  c-stride 64 == 0 (mod 8): all 10 c-copies of
// an x-chunk land on one XCD (L2 reuse).  NB=4 (full batch per block):
// the 8 W-broadcast b128 reads per r amortize over 128 fma.
// ===========================================================================
template <bool UNIFORM>
__global__ __launch_bounds__(256) void k_s9(const float* __restrict__ xT,
                                            const float* __restrict__ Wm,
                                            const float* __restrict__ bijT,
                                            float* __restrict__ s_dst) {
    __shared__ __align__(16) float wl[RC_ * 128];   // 9.2 KB
    __shared__ float cwch[RC_];
    __shared__ float sred[8];

    const int tid  = threadIdx.x;
    const int lane = tid & 63;
    const int bid  = blockIdx.x;
    const int c    = bid >> 6;            // 0..9
    const int ks   = bid & 63;            // 0..63
    const int r0   = ks * RC_;

    // ---- per-block softmax over routes for capsule c -> cwch[0..17] ----
    if (!UNIFORM) {
        const float* bc = bijT + (size_t)c * R_;
        float bv[5];
        float m = -1e30f;
        #pragma unroll
        for (int k = 0; k < 5; ++k) {
            const int r = tid + 256 * k;
            bv[k] = (r < R_) ? bc[r] : -1e30f;
            m = fmaxf(m, bv[k]);
        }
        #pragma unroll
        for (int off = 32; off > 0; off >>= 1)
            m = fmaxf(m, __shfl_down(m, off, 64));
        if (lane == 0) sred[tid >> 6] = m;
        __syncthreads();
        const float bm = fmaxf(fmaxf(sred[0], sred[1]), fmaxf(sred[2], sred[3]));
        float se = 0.f;
        #pragma unroll
        for (int k = 0; k < 5; ++k)
            se += (bv[k] > -1e29f) ? expf(bv[k] - bm) : 0.f;
        #pragma unroll
        for (int off = 32; off > 0; off >>= 1)
            se += __shfl_down(se, off, 64);
        if (lane == 0) sred[4 + (tid >> 6)] = se;
        __syncthreads();
        const float inv = 1.0f / (sred[4] + sred[5] + sred[6] + sred[7]);
        if (tid < RC_) cwch[tid] = expf(bc[r0 + tid] - bm) * inv;
        __syncthreads();
    }

    // ---- stage cw-scaled W chunk: 18 r x 32 f4 = 576 f4 ----
    {
        const float4* src = (const float4*)(Wm + ((size_t)r0 * C_ + c) * 128);
        float4* dst = (float4*)wl;
        #pragma unroll
        for (int k = 0; k < (RC_ * 32 + 255) / 256; ++k) {
            const int idx = tid + 256 * k;
            if (idx < RC_ * 32) {
                const int r = idx >> 5, q = idx & 31;
                float4 wv = src[(size_t)r * (C_ * 32) + q];
                const float cw = UNIFORM ? (1.0f / (float)R_) : cwch[r];
                wv.x *= cw; wv.y *= cw; wv.z *= cw; wv.w *= cw;
                dst[idx] = wv;
            }
        }
    }
    __syncthreads();

    const int o0 = (tid >> 6) * 4;        // wave-uniform -> LDS broadcast reads
    const float* xbase = xT + ((size_t)r0 * B_ + lane) * I_;

    float acc[4][4];                      // [oo][bb]
    #pragma unroll
    for (int oo = 0; oo < 4; ++oo)
        #pragma unroll
        for (int bb = 0; bb < 4; ++bb) acc[oo][bb] = 0.f;

    #pragma unroll 2
    for (int r = 0; r < RC_; ++r) {
        const float* xr = xbase + (size_t)r * B_ * I_;
        float4 xa[4][2];
        #pragma unroll
        for (int bb = 0; bb < 4; ++bb) {
            const float4* xp = (const float4*)(xr + (size_t)bb * 64 * I_);
            xa[bb][0] = xp[0];
            xa[bb][1] = xp[1];
        }
        const float4* wp = (const float4*)&wl[r * 128 + o0 * 8];
        #pragma unroll
        for (int oo = 0; oo < 4; ++oo) {
            const float4 w0 = wp[oo * 2 + 0];
            const float4 w1 = wp[oo * 2 + 1];
            #pragma unroll
            for (int bb = 0; bb < 4; ++bb) {
                float a = acc[oo][bb];
                a = fmaf(xa[bb][0].x, w0.x, a);
                a = fmaf(xa[bb][0].y, w0.y, a);
                a = fmaf(xa[bb][0].z, w0.z, a);
                a = fmaf(xa[bb][0].w, w0.w, a);
                a = fmaf(xa[bb][1].x, w1.x, a);
                a = fmaf(xa[bb][1].y, w1.y, a);
                a = fmaf(xa[bb][1].z, w1.z, a);
                a = fmaf(xa[bb][1].w, w1.w, a);
                acc[oo][bb] = a;
            }
        }
    }

    float* sp = s_dst + (size_t)(c * O_ + o0) * B_ + lane;
    #pragma unroll
    for (int oo = 0; oo < 4; ++oo)
        #pragma unroll
        for (int bb = 0; bb < 4; ++bb)
            atomicAdd(sp + (size_t)oo * B_ + bb * 64, acc[oo][bb]);
}

// ===========================================================================
// k_vt: vT[b][co] = squash(s[co][b]).  Transpose+squash so the a-kernel's
// per-thread 4-co read becomes ONE coalesced float4.
// grid 20 = 5 co-tiles(32) x 4 b-tiles(64), 256 thr.
// ===========================================================================
__global__ __launch_bounds__(256) void k_vt(const float* __restrict__ s,
                                            float* __restrict__ vT) {
    __shared__ float t[32][65];
    const int tid  = threadIdx.x;
    const int co0  = (blockIdx.x % 5) * 32;
    const int b0   = (blockIdx.x / 5) * 64;
    const int lane = tid & 63;
    const int g    = tid >> 6;            // 0..3
    #pragma unroll
    for (int k = 0; k < 8; ++k) {
        const int co = g + k * 4;
        t[co][lane] = s[(size_t)(co0 + co) * B_ + b0 + lane];
    }
    __syncthreads();
    const int bl  = tid >> 2;             // 0..63
    const int coq = (tid & 3) * 8;        // 0,8,16,24
    float* dst = vT + (size_t)(b0 + bl) * CO_ + co0 + coq;
    float4 o0, o1;
    o0.x = squash_fast(t[coq + 0][bl]);
    o0.y = squash_fast(t[coq + 1][bl]);
    o0.z = squash_fast(t[coq + 2][bl]);
    o0.w = squash_fast(t[coq + 3][bl]);
    o1.x = squash_fast(t[coq + 4][bl]);
    o1.y = squash_fast(t[coq + 5][bl]);
    o1.z = squash_fast(t[coq + 6][bl]);
    o1.w = squash_fast(t[coq + 7][bl]);
    *(float4*)dst = o0;
    *(float4*)(dst + 4) = o1;
}

// ===========================================================================
// k_a10: bijT[c][r] += (1/B) sum_{o,i} W[r,c,o,i] *
//        (sum_b vT[b][co] * xT[r,b,i])
// grid 1152 = one route per block (uniform, ~4 blocks/CU resident).
// 320 thr = 40 co-quads x 8 b-groups of 32.  v reads: one coalesced f4 per
// (b, co-quad) from vT (pre-squashed).  x in XOR-swizzled LDS (8 KB).
// bij single-writer per r -> plain += (no atomics, no fences).
// ===========================================================================
struct A10Sh {
    float4 xsw[512];         // swizzled x: 256 b x 8 i (8 KB)
    float  part[320];
};

__global__ __launch_bounds__(320) void k_a10(const float* __restrict__ xT,
                                             const float* __restrict__ Wm,
                                             const float* __restrict__ vT,
                                             float* __restrict__ s_zero,
                                             float* __restrict__ bijT) {
    __shared__ A10Sh sh;
    const int tid = threadIdx.x;
    const int r   = blockIdx.x;

    if (s_zero != nullptr && r < 40 && tid < 256) {
        ((float4*)s_zero)[r * 256 + tid] = make_float4(0.f, 0.f, 0.f, 0.f);
    }

    // ---- stage x[r], swizzled: slot = k ^ ((k>>6)&7); k = 2b+ih ----
    {
        const float4* src = (const float4*)(xT + (size_t)r * B_ * I_);
        for (int k = tid; k < 512; k += 320)
            sh.xsw[k ^ ((k >> 6) & 7)] = src[k];
    }
    __syncthreads();

    const int cq = tid % 40;          // co quad: co = 4cq..4cq+3 (one capsule)
    const int bg = tid / 40;          // 0..7, 32 b each
    const int b0 = bg * 32;

    float acc[4][8];
    #pragma unroll
    for (int j = 0; j < 4; ++j)
        #pragma unroll
        for (int i = 0; i < 8; ++i) acc[j][i] = 0.f;

    const float* vb = vT + (size_t)b0 * CO_ + 4 * cq;

    #pragma unroll 2
    for (int bb = 0; bb < 32; bb += 4) {
        float va[4][4];               // [b j2][co j]
        #pragma unroll
        for (int j2 = 0; j2 < 4; ++j2) {
            const float4 t = *(const float4*)(vb + (size_t)(bb + j2) * CO_);
            va[j2][0] = t.x; va[j2][1] = t.y; va[j2][2] = t.z; va[j2][3] = t.w;
        }
        #pragma unroll
        for (int j2 = 0; j2 < 4; ++j2) {
            const int e0 = ((b0 + bb + j2) * 2) ^ bg;
            const float4 x0 = sh.xsw[e0];
            const float4 x1 = sh.xsw[e0 ^ 1];
            #pragma unroll
            for (int j = 0; j < 4; ++j) {
                const float w = va[j2][j];
                acc[j][0] = fmaf(w, x0.x, acc[j][0]);
                acc[j][1] = fmaf(w, x0.y, acc[j][1]);
                acc[j][2] = fmaf(w, x0.z, acc[j][2]);
                acc[j][3] = fmaf(w, x0.w, acc[j][3]);
                acc[j][4] = fmaf(w, x1.x, acc[j][4]);
                acc[j][5] = fmaf(w, x1.y, acc[j][5]);
                acc[j][6] = fmaf(w, x1.z, acc[j][6]);
                acc[j][7] = fmaf(w, x1.w, acc[j][7]);
            }
        }
    }

    // ---- W-dot epilogue: thread's 4 co are within one capsule ----
    {
        const float* wp = Wm + ((size_t)r * CO_ + 4 * cq) * I_;
        float psum = 0.f;
        #pragma unroll
        for (int j = 0; j < 4; ++j) {
            const float4 w0 = *(const float4*)(wp + j * 8);
            const float4 w1 = *(const float4*)(wp + j * 8 + 4);
            float p = acc[j][0] * w0.x;
            p = fmaf(acc[j][1], w0.y, p);
            p = fmaf(acc[j][2], w0.z, p);
            p = fmaf(acc[j][3], w0.w, p);
            p = fmaf(acc[j][4], w1.x, p);
            p = fmaf(acc[j][5], w1.y, p);
            p = fmaf(acc[j][6], w1.z, p);
            p = fmaf(acc[j][7], w1.w, p);
            psum += p;
        }
        sh.part[tid] = psum;
    }
    __syncthreads();

    // reduce per capsule: 8 bg x 4 cq-of-capsule = 32 partials
    if (tid < C_) {
        float s = 0.f;
        #pragma unroll
        for (int g2 = 0; g2 < 8; ++g2)
            #pragma unroll
            for (int q = 0; q < 4; ++q)
                s += sh.part[g2 * 40 + tid * 4 + q];
        bijT[(size_t)tid * R_ + r] += s * (1.0f / (float)B_);
    }
}

// ===========================================================================
// k_sqout: out[b,co] = squash(s[co][b]).  grid 160 (=co), 256 thr (=b).
// ===========================================================================
__global__ __launch_bounds__(256) void k_sqout(const float* __restrict__ s,
                                               float* __restrict__ out) {
    const int co = blockIdx.x;
    const int b  = threadIdx.x;
    out[(size_t)b * CO_ + co] = squash_fast(s[(size_t)co * B_ + b]);
}

// ===========================================================================
// FALLBACK tier 3 (tiny ws)
// ===========================================================================
template <bool UNIFORM>
__global__ __launch_bounds__(256) void k_s_f(const float* __restrict__ x,
                                             const float* __restrict__ Wm,
                                             const float* __restrict__ cij,
                                             float* __restrict__ s_out) {
    const int o  = threadIdx.x & 15;
    const int tb = threadIdx.x >> 4;
    const int b  = blockIdx.z * MBF_ + tb;
    const int c  = blockIdx.y;
    const int r0 = blockIdx.x * RCF_;

    const float* xp = x + ((size_t)b * R_ + r0) * I_;
    const float* wp = Wm + (((size_t)r0 * C_ + c) * O_ + o) * I_;
    const float* cp = cij + (size_t)r0 * C_ + c;

    float acc = 0.f;
    #pragma unroll 4
    for (int r = 0; r < RCF_; ++r) {
        const float4 xv0 = *(const float4*)(xp);
        const float4 xv1 = *(const float4*)(xp + 4);
        const float4 wv0 = *(const float4*)(wp);
        const float4 wv1 = *(const float4*)(wp + 4);
        const float p0 = fmaf(xv0.y, wv0.y, xv0.x * wv0.x);
        const float p1 = fmaf(xv0.w, wv0.w, xv0.z * wv0.z);
        const float p2 = fmaf(xv1.y, wv1.y, xv1.x * wv1.x);
        const float p3 = fmaf(xv1.w, wv1.w, xv1.z * wv1.z);
        const float cw = UNIFORM ? (1.0f / (float)R_) : cp[0];
        acc = fmaf(cw, (p0 + p1) + (p2 + p3), acc);
        xp += I_;
        wp += WRI_;
        cp += C_;
    }
    atomicAdd(&s_out[((size_t)b * C_ + c) * O_ + o], acc);
}

__global__ __launch_bounds__(256) void k_a_f(const float* __restrict__ x,
                                             const float* __restrict__ Wm,
                                             const float* __restrict__ s_in,
                                             float* __restrict__ amean) {
    __shared__ __align__(16) float wlds[2 * WRI_];
    __shared__ float red[4][2 * C_];

    const int tid = threadIdx.x;
    const int r0  = blockIdx.x * 2;

    const float* wsrc = Wm + (size_t)r0 * WRI_;
    #pragma unroll
    for (int k = 0; k < 2 * WRI_ / 256; ++k)
        wlds[tid + 256 * k] = wsrc[tid + 256 * k];
    __syncthreads();

    const int b    = tid;
    const int lane = tid & 63;
    const int wv   = tid >> 6;

    float xv[2][I_];
    const float4* xp4 = (const float4*)(x + ((size_t)b * R_ + r0) * I_);
    #pragma unroll
    for (int rr = 0; rr < 2; ++rr) {
        const float4 a0 = xp4[rr * 2 + 0];
        const float4 a1 = xp4[rr * 2 + 1];
        xv[rr][0] = a0.x; xv[rr][1] = a0.y; xv[rr][2] = a0.z; xv[rr][3] = a0.w;
        xv[rr][4] = a1.x; xv[rr][5] = a1.y; xv[rr][6] = a1.z; xv[rr][7] = a1.w;
    }

    #pragma unroll 1
    for (int c = 0; c < C_; ++c) {
        const float4* sp4 = (const float4*)(s_in + ((size_t)b * C_ + c) * O_);
        float v[O_];
        #pragma unroll
        for (int q = 0; q < 4; ++q) {
            const float4 sv = sp4[q];
            v[q * 4 + 0] = squashf(sv.x);
            v[q * 4 + 1] = squashf(sv.y);
            v[q * 4 + 2] = squashf(sv.z);
            v[q * 4 + 3] = squashf(sv.w);
        }
        #pragma unroll 1
        for (int rr = 0; rr < 2; ++rr) {
            const float4* wl4 = (const float4*)&wlds[(rr * C_ + c) * O_ * I_];
            float a = 0.f;
            #pragma unroll
            for (int o = 0; o < O_; ++o) {
                const float4 w0 = wl4[o * 2 + 0];
                const float4 w1 = wl4[o * 2 + 1];
                float u = xv[rr][0] * w0.x;
                u = fmaf(xv[rr][1], w0.y, u);
                u = fmaf(xv[rr][2], w0.z, u);
                u = fmaf(xv[rr][3], w0.w, u);
                u = fmaf(xv[rr][4], w1.x, u);
                u = fmaf(xv[rr][5], w1.y, u);
                u = fmaf(xv[rr][6], w1.z, u);
                u = fmaf(xv[rr][7], w1.w, u);
                a = fmaf(u, v[o], a);
            }
            #pragma unroll
            for (int off = 32; off > 0; off >>= 1)
                a += __shfl_down(a, off, 64);
            if (lane == 0) red[wv][rr * C_ + c] = a;
        }
    }

    __syncthreads();
    if (tid < 2 * C_) {
        const float t = red[0][tid] + red[1][tid] + red[2][tid] + red[3][tid];
        const int rr = tid / C_;
        const int c  = tid % C_;
        amean[(size_t)(r0 + rr) * C_ + c] = t * (1.0f / (float)B_);
    }
}

__global__ __launch_bounds__(256) void k_soft(const float* __restrict__ amean,
                                              float* __restrict__ bij,
                                              float* __restrict__ cij) {
    const int c   = blockIdx.x;
    const int tid = threadIdx.x;
    __shared__ float sred[4];

    float vals[5];
    float m = -1e30f;
    #pragma unroll
    for (int k = 0; k < 5; ++k) {
        const int r = tid + 256 * k;
        if (r < R_) {
            const size_t idx = (size_t)r * C_ + c;
            const float vv = bij[idx] + amean[idx];
            bij[idx] = vv;
            vals[k] = vv;
            m = fmaxf(m, vv);
        } else {
            vals[k] = -1e30f;
        }
    }
    #pragma unroll
    for (int off = 32; off > 0; off >>= 1)
        m = fmaxf(m, __shfl_down(m, off, 64));
    if ((tid & 63) == 0) sred[tid >> 6] = m;
    __syncthreads();
    const float bm = fmaxf(fmaxf(sred[0], sred[1]), fmaxf(sred[2], sred[3]));
    __syncthreads();

    float se = 0.f;
    #pragma unroll
    for (int k = 0; k < 5; ++k)
        se += (vals[k] > -1e29f) ? expf(vals[k] - bm) : 0.f;
    #pragma unroll
    for (int off = 32; off > 0; off >>= 1)
        se += __shfl_down(se, off, 64);
    if ((tid & 63) == 0) sred[tid >> 6] = se;
    __syncthreads();
    const float inv = 1.0f / (sred[0] + sred[1] + sred[2] + sred[3]);

    #pragma unroll
    for (int k = 0; k < 5; ++k) {
        const int r = tid + 256 * k;
        if (r < R_) cij[(size_t)r * C_ + c] = expf(vals[k] - bm) * inv;
    }
}

__global__ __launch_bounds__(256) void k_squash(float* __restrict__ s) {
    const int idx = blockIdx.x * 256 + threadIdx.x;
    if (idx < B_ * CO_) s[idx] = squashf(s[idx]);
}

} // namespace

extern "C" void kernel_launch(void* const* d_in, const int* in_sizes, int n_in,
                              void* d_out, int out_size, void* d_ws, size_t ws_size,
                              hipStream_t stream) {
    const float* x  = (const float*)d_in[0];   // [256,1152,8]
    const float* Wm = (const float*)d_in[1];   // [1152,10,16,8]
    float* out = (float*)d_out;                // [256,10,16] flat = 40960
    float* ws  = (float*)d_ws;

    const size_t need = FL_TOTAL * sizeof(float);

    if (ws_size >= need) {
        // ---------------- main path: 9 nodes ----------------
        float* xT   = ws + XT_OFF;
        float* sA   = ws + SA_OFF;
        float* sB   = ws + SB_OFF;
        float* bijT = ws + BIJ_OFF;
        float* vTb  = ws + VT_OFF;

        k_tr<<<1152, 256, 0, stream>>>(x, xT, sA /* = zbase, zeroes sA|sB|bij */);

        // iter 0 (uniform weights; softmax(0) == 1/R)
        k_s9<true><<<C_ * KS_, 256, 0, stream>>>(xT, Wm, bijT, sA);
        k_vt<<<20, 256, 0, stream>>>(sA, vTb);
        k_a10<<<R_, 320, 0, stream>>>(xT, Wm, vTb, nullptr, bijT);

        // iter 1  (sB zeroed by k_tr)
        k_s9<false><<<C_ * KS_, 256, 0, stream>>>(xT, Wm, bijT, sB);
        k_vt<<<20, 256, 0, stream>>>(sB, vTb);
        k_a10<<<R_, 320, 0, stream>>>(xT, Wm, vTb, sA /* zero for iter 2 */, bijT);

        // iter 2
        k_s9<false><<<C_ * KS_, 256, 0, stream>>>(xT, Wm, bijT, sA);
        k_sqout<<<CO_, 256, 0, stream>>>(sA, out);
    } else {
        // ---------------- tier 3 ----------------
        float* s_buf = ws;
        float* cij   = ws + 40960;
        float* bij   = cij + R_ * C_;
        float* amean = bij + R_ * C_;

        const dim3 gsf(KSF_, C_, B_ / MBF_);

        hipMemsetAsync(bij, 0, R_ * C_ * sizeof(float), stream);

        hipMemsetAsync(s_buf, 0, B_ * CO_ * sizeof(float), stream);
        k_s_f<true><<<gsf, 256, 0, stream>>>(x, Wm, cij, s_buf);
        k_a_f<<<R_ / 2, 256, 0, stream>>>(x, Wm, s_buf, amean);
        k_soft<<<C_, 256, 0, stream>>>(amean, bij, cij);

        hipMemsetAsync(s_buf, 0, B_ * CO_ * sizeof(float), stream);
        k_s_f<false><<<gsf, 256, 0, stream>>>(x, Wm, cij, s_buf);
        k_a_f<<<R_ / 2, 256, 0, stream>>>(x, Wm, s_buf, amean);
        k_soft<<<C_, 256, 0, stream>>>(amean, bij, cij);

        hipMemsetAsync(out, 0, B_ * CO_ * sizeof(float), stream);
        k_s_f<false><<<gsf, 256, 0, stream>>>(x, Wm, cij, out);
        k_squash<<<(B_ * CO_ + 255) / 256, 256, 0, stream>>>(out);
    }
}